// Round 15
// baseline (1682.752 us; speedup 1.0000x reference)
//
#include <hip/hip_runtime.h>
#include <hip/hip_bf16.h>
#include <cstddef>

// Problem constants
#define B_  256
#define T_  256
#define D_  256
#define H_  384
#define G_  1542
#define L_  3
#define CH_ 128
#define K_  10
#define HS_ 64

// Serial-phase geometry: 16 groups (16 b each) x 16 members (24 ch, 102 cols -> 7 frags)
#define NGRP 16
#define NMEM 16
#define GW   16
#define CPM  24
#define NFR  7
#define PCOLS 112
#define XOLP 114
#define NKC  20
// k_serial LDS layout (bytes)
#define W_LDS    (NKC * NFR * 64 * 8 * 2)   // 143360
#define BIAS_OFF W_LDS
#define UNI_OFF  (W_LDS + 512)              // union: stage 12 slots (12288) / xol (7296)
#define LDS_BYTES (UNI_OFF + 12288)         // 156160

// k_post LDS: ldl 5120 | Al dbuf 20480 | Bl dbuf 61440 -> 87040 (conv)
//             epilogue: hbarL@5120 (51200) uL@56320 (9216) -> 65536
#define POST_LDS 87040

#define SENT 0xFFFFFFFFFFFFFFFFull

using bf16x8 = __attribute__((ext_vector_type(8))) short;
using f32x4  = __attribute__((ext_vector_type(4))) float;
typedef unsigned long long ull_t;

__device__ __forceinline__ float bf2f(unsigned short s) {
    return __uint_as_float(((unsigned)s) << 16);
}
__device__ __forceinline__ unsigned short f2bf(float f) {
    unsigned u = __float_as_uint(f);
    return (unsigned short)((u + 0x7fffu + ((u >> 16) & 1u)) >> 16);
}
__device__ __forceinline__ float sig_fast(float x) { return 1.f / (1.f + __expf(-x)); }
__device__ __forceinline__ float tanh_fast(float x) {
    float ax = fabsf(x);
    float t = __expf(-2.f * ax);
    float r = (1.f - t) / (1.f + t);
    return copysignf(r, x);
}
__device__ __forceinline__ ull_t ldA(const ull_t* p) {
    return __hip_atomic_load(p, __ATOMIC_RELAXED, __HIP_MEMORY_SCOPE_AGENT);
}
// ready iff NO 16-bit field of v equals 0xFFFF (bf16 -NaN sentinel; h in (-1,1) can't encode it)
__device__ __forceinline__ bool rdy(ull_t v) {
    ull_t x = ~v;
    return (((x - 0x0001000100010001ull) & ~x & 0x8000800080008000ull) == 0ull);
}

// packed col -> gate col (or -1 for pad)
__device__ __forceinline__ int gcol_of(int member, int p) {
    if (p < 6) return p;
    if (p < 102) { int q = p - 6; return 6 + (q / CPM) * H_ + member * CPM + (q % CPM); }
    return -1;
}

// ---------------- xA: A-frag-ordered x (bf16), coalesced via LDS ----------------
__global__ __launch_bounds__(256)
void k_xa(const float* __restrict__ x, unsigned short* __restrict__ xA) {
    __shared__ float xl[64][261];
    const int t = blockIdx.x, bq = blockIdx.y;
    const int b0 = bq * 64, tid = threadIdx.x;
    for (int idx = tid; idx < 4096; idx += 256) {
        int row = idx >> 6, c4 = idx & 63;
        float4 v = *(const float4*)(x + ((size_t)(b0 + row) * T_ + t) * D_ + c4 * 4);
        xl[row][c4 * 4 + 0] = v.x; xl[row][c4 * 4 + 1] = v.y;
        xl[row][c4 * 4 + 2] = v.z; xl[row][c4 * 4 + 3] = v.w;
    }
    __syncthreads();
    for (int idx = tid; idx < 2048; idx += 256) {
        int lane = idx & 63, gl = (idx >> 6) & 3, kc = idx >> 8;
        int brow = gl * 16 + (lane & 15);
        int d = kc * 32 + (lane >> 4) * 8;
        unsigned o[4];
        #pragma unroll
        for (int q = 0; q < 4; ++q)
            o[q] = (unsigned)f2bf(xl[brow][d + 2 * q])
                 | ((unsigned)f2bf(xl[brow][d + 2 * q + 1]) << 16);
        int4 pk = make_int4((int)o[0], (int)o[1], (int)o[2], (int)o[3]);
        ((int4*)xA)[(((size_t)t * 8 + kc) * 16 + (bq * 4 + gl)) * 64 + lane] = pk;
    }
}

// ---------------- merged prep: hbf sentinel + wfrag + wg + wst + wrst + bias -------
__global__ __launch_bounds__(256)
void k_prep(const float* __restrict__ Wk, const float* __restrict__ bk,
            const float* __restrict__ Wr, const float* __restrict__ br,
            const float* __restrict__ Ws, const float* __restrict__ Wrs,
            const float* __restrict__ Wc,
            unsigned short* __restrict__ hbf, unsigned short* __restrict__ Wf,
            unsigned short* __restrict__ Wg, unsigned short* __restrict__ WsT,
            unsigned short* __restrict__ WrsT, float* __restrict__ biasP)
{
    const int bid = blockIdx.x, tid = threadIdx.x;
    if (bid < 2048) {
        ull_t* hb = (ull_t*)hbf;
        int base = bid * 256 + tid;
        #pragma unroll
        for (int j = 0; j < 12; ++j)
            __hip_atomic_store(hb + base + j * 524288, SENT,
                               __ATOMIC_RELAXED, __HIP_MEMORY_SCOPE_AGENT);
    } else if (bid < 2608) {
        int idx = (bid - 2048) * 256 + tid;          // < 143360
        int lane = idx & 63;
        int ni   = (idx >> 6) % NFR;
        int kc   = (idx / (64 * NFR)) % NKC;
        int member = idx / (64 * NFR * NKC);
        int p = ni * 16 + (lane & 15);
        int g = gcol_of(member, p);
        unsigned short out[8];
        #pragma unroll
        for (int j = 0; j < 8; ++j) {
            int k = kc * 32 + (lane >> 4) * 8 + j;
            float v = 0.f;
            if (g >= 0) v = (k < 256) ? Wk[(size_t)k * G_ + g] : Wr[(size_t)(k - 256) * G_ + g];
            out[j] = f2bf(v);
        }
        int4 pk;
        pk.x = (unsigned)out[0] | ((unsigned)out[1] << 16);
        pk.y = (unsigned)out[2] | ((unsigned)out[3] << 16);
        pk.z = (unsigned)out[4] | ((unsigned)out[5] << 16);
        pk.w = (unsigned)out[6] | ((unsigned)out[7] << 16);
        ((int4*)Wf)[idx] = pk;
    } else if (bid < 8368) {
        int idx = (bid - 2608) * 256 + tid;          // < 1474560
        int o = idx / (K_ * H_);
        int rem = idx % (K_ * H_);
        int k = rem / H_, h = rem % H_;
        Wg[idx] = f2bf(Wc[((size_t)o * H_ + h) * K_ + k]);
    } else if (bid < 8464) {
        int idx = (bid - 8368) * 256 + tid;          // < 24576
        int jj = idx / H_, k = idx % H_;
        WsT[idx] = f2bf(Ws[(size_t)k * HS_ + jj]);
    } else if (bid < 8560) {
        int idx = (bid - 8464) * 256 + tid;          // < 24576
        int o = idx / HS_, jj = idx % HS_;
        WrsT[idx] = f2bf(Wrs[(size_t)jj * H_ + o]);
    } else {
        int idx = (bid - 8560) * 256 + tid;
        if (idx < NMEM * PCOLS) {
            int member = idx / PCOLS, p = idx % PCOLS;
            int g = gcol_of(member, p);
            biasP[idx] = (g >= 0)
                ? bk[g] + br[g] + Wk[(size_t)256 * G_ + g] + Wr[(size_t)384 * G_ + g] : 0.f;
        }
    }
}

// ---------------- persistent serial recurrence (direct-publish sentinel protocol) ---
__global__ __launch_bounds__(512, 1)
void k_serial(const unsigned short* __restrict__ xA, const unsigned short* __restrict__ Wf,
              const float* __restrict__ biasP,
              unsigned short* __restrict__ hbf, float* __restrict__ dis)
{
    extern __shared__ char lds_raw[];
    unsigned short* Wl = (unsigned short*)lds_raw;
    float* biasL = (float*)(lds_raw + BIAS_OFF);
    char* uni = lds_raw + UNI_OFF;
    float* xol = (float*)uni;                                   // 16 x 114 f32 (< 12288)
    int4* stage4 = (int4*)uni;                                  // 12 kc x 64 lanes x 16B
    const bf16x8* stage = (const bf16x8*)uni;

    const int tid = threadIdx.x;
    const int lane = tid & 63, wave = tid >> 6;
    const int group = blockIdx.x & 15, member = blockIdx.x >> 4;
    const int b0 = group * GW;
    const int ni = wave;
    const bool domm = (wave < NFR);

    {
        const int4* src = (const int4*)(Wf + (size_t)member * (NKC * NFR * 64 * 8));
        for (int i = tid; i < W_LDS / 16; i += 512) ((int4*)Wl)[i] = src[i];
        if (tid < PCOLS) biasL[tid] = biasP[member * PCOLS + tid];
    }
    __syncthreads();

    const float bias_a = domm ? biasL[ni * 16 + (lane & 15)] : 0.f;

    const bool hasS = (tid < 384);
    const int skcl = tid >> 6, sln = tid & 63;
    const int stA = skcl * 64 + sln;
    const int stB = (skcl + 6) * 64 + sln;
    const unsigned short* src0 =
        hbf + (size_t)(b0 + (sln & 15)) * H_ + skcl * 32 + (sln >> 4) * 8;

    float c_r0 = 0.f;

    for (int t = 0; t < T_; ++t) {
        bf16x8 xf[8];
        if (domm) {
            #pragma unroll
            for (int kc = 0; kc < 8; ++kc)
                xf[kc] = *((const bf16x8*)(xA
                    + (((size_t)t * 8 + kc) * 16 + group) * 512 + lane * 8));
        }

        // dual accumulator chains (break MFMA dep latency)
        f32x4 accA = f32x4{bias_a, bias_a, bias_a, bias_a};
        f32x4 accB = f32x4{0.f, 0.f, 0.f, 0.f};

        if (t > 0) {
            const size_t toff = (size_t)(t - 1) * B_ * H_;
            const ull_t* pA = (const ull_t*)(src0 + toff);
            const ull_t* pB = (const ull_t*)(src0 + toff + 192);
            ull_t v0 = SENT, v1 = SENT, v2 = SENT, v3 = SENT;
            if (hasS) { v0 = ldA(pA); v1 = ldA(pA + 1); v2 = ldA(pB); v3 = ldA(pB + 1); }

            if (domm) {
                #pragma unroll
                for (int kc = 0; kc < 8; ++kc) {
                    bf16x8 w0 = ((const bf16x8*)Wl)[(kc * NFR + ni) * 64 + lane];
                    if (kc & 1)
                        accB = __builtin_amdgcn_mfma_f32_16x16x32_bf16(xf[kc], w0, accB, 0, 0, 0);
                    else
                        accA = __builtin_amdgcn_mfma_f32_16x16x32_bf16(xf[kc], w0, accA, 0, 0, 0);
                }
            }

            if (hasS) {
                while (!(rdy(v0) && rdy(v1) && rdy(v2) && rdy(v3))) {
                    v0 = ldA(pA); v1 = ldA(pA + 1); v2 = ldA(pB); v3 = ldA(pB + 1);
                }
                stage4[stA] = make_int4((int)(v0 & 0xffffffffu), (int)(v0 >> 32),
                                        (int)(v1 & 0xffffffffu), (int)(v1 >> 32));
                stage4[stB] = make_int4((int)(v2 & 0xffffffffu), (int)(v2 >> 32),
                                        (int)(v3 & 0xffffffffu), (int)(v3 >> 32));
            }
            __syncthreads();                                    // S1: stage ready
            if (domm) {
                #pragma unroll
                for (int kcl = 0; kcl < 12; ++kcl) {
                    bf16x8 a0 = stage[kcl * 64 + lane];
                    bf16x8 w0 = ((const bf16x8*)Wl)[((8 + kcl) * NFR + ni) * 64 + lane];
                    if (kcl & 1)
                        accB = __builtin_amdgcn_mfma_f32_16x16x32_bf16(a0, w0, accB, 0, 0, 0);
                    else
                        accA = __builtin_amdgcn_mfma_f32_16x16x32_bf16(a0, w0, accA, 0, 0, 0);
                }
            }
            __syncthreads();                                    // S2: stage dead
        } else {
            if (domm) {
                #pragma unroll
                for (int kc = 0; kc < 8; ++kc) {
                    bf16x8 w0 = ((const bf16x8*)Wl)[(kc * NFR + ni) * 64 + lane];
                    if (kc & 1)
                        accB = __builtin_amdgcn_mfma_f32_16x16x32_bf16(xf[kc], w0, accB, 0, 0, 0);
                    else
                        accA = __builtin_amdgcn_mfma_f32_16x16x32_bf16(xf[kc], w0, accA, 0, 0, 0);
                }
            }
        }

        if (domm) {
            #pragma unroll
            for (int r = 0; r < 4; ++r)
                xol[((lane >> 4) * 4 + r) * XOLP + ni * 16 + (lane & 15)] = accA[r] + accB[r];
        }
        __syncthreads();                                        // S3: xol ready

        // ---- gates: 384 items; DIRECT publication (paired u32 agent stores) ----
        if (tid < 384) {
            int b = tid & 15, ch = tid >> 4;
            const float* row = xol + b * XOLP;
            float z0 = row[0], z1 = row[1], z2 = row[2];
            float z3 = row[3], z4 = row[4], z5 = row[5];
            float m1 = fmaxf(fmaxf(z0, z1), z2);
            float e0 = __expf(z0 - m1), e1 = __expf(z1 - m1), e2 = __expf(z2 - m1);
            float inv1 = 1.f / (e0 + e1 + e2);
            float fm0 = e0 * inv1, fm1 = (e0 + e1) * inv1;
            float m2 = fmaxf(fmaxf(z3, z4), z5);
            float f3 = __expf(z3 - m2), f4 = __expf(z4 - m2), f5 = __expf(z5 - m2);
            float inv2 = 1.f / (f3 + f4 + f5);
            float im1 = (f4 + f5) * inv2, im2 = f5 * inv2;

            int hh = member * CPM + ch;
            int l = hh >> 7;
            float fm = (l == 0) ? fm0 : (l == 1) ? fm1 : 1.f;
            float im = (l == 0) ? 1.f : (l == 1) ? im1 : im2;

            float fg = sig_fast(row[6 + ch]);
            float ig = sig_fast(row[6 + CPM + ch]);
            float og = sig_fast(row[6 + 2 * CPM + ch]);
            float ci = tanh_fast(row[6 + 3 * CPM + ch]);

            float ov = fm * im;
            float cn = ov * (fg * c_r0 + ig * ci) + (fm - ov) * c_r0 + (im - ov) * ci;
            float hn = og * tanh_fast(cn);
            c_r0 = cn;

            unsigned hpk = (unsigned)f2bf(hn);
            unsigned partner = (unsigned)__shfl((int)hpk, (lane + 16) & 63);
            if (!(ch & 1)) {
                unsigned word = hpk | (partner << 16);
                __hip_atomic_store(
                    (unsigned*)(hbf + ((size_t)t * B_ + b0 + b) * H_ + hh),
                    word, __ATOMIC_RELAXED, __HIP_MEMORY_SCOPE_AGENT);
            }
            if (member == 0 && ch == 0)
                dis[t * B_ + b0 + b] = 1.f - (fm0 + fm1 + 1.f) * (1.f / 3.f);
        }
        // no trailing sync: consumers spin on the data itself
    }
}

// ---------------- fused post: depth-2-prefetch conv (dbuf) + hbar + theme + combine -
// block = (64 b, 2 t), 512 threads, 8 waves (wave tile 32b x 96o). grid (4, 128).
// Pipeline: loads for chunk ch+3 issued at iter ch (2 reg sets in flight); LDS writes
// for ch+1 happen BEFORE the single per-chunk barrier. ~800cy of latency hidden.
__global__ __launch_bounds__(512, 1)
void k_post(const unsigned short* __restrict__ hbf, const float* __restrict__ dis,
            const unsigned short* __restrict__ Wg,
            const unsigned short* __restrict__ WsT, const unsigned short* __restrict__ WrsT,
            const float* __restrict__ bs, const float* __restrict__ brs,
            const float* __restrict__ bc, float* __restrict__ out_part)
{
    extern __shared__ char plds[];
    float* ldl = (float*)plds;                                   // [2][64][10] 5120
    unsigned short* AlB = (unsigned short*)(plds + 5120);        // [2][2][64][40] 20480
    unsigned short* BlB = (unsigned short*)(plds + 25600);       // [2][384][40] 61440
    unsigned short* hbarL = (unsigned short*)(plds + 5120);      // [64][400] (post-conv)
    unsigned short* uL = (unsigned short*)(plds + 56320);        // [64][72]

    const int b0 = blockIdx.x * 64;
    const int t0 = blockIdx.y * 2;
    const int tid = threadIdx.x;
    const int wave = tid >> 6, lane = tid & 63;
    const int mh = wave >> 2, nq = wave & 3;

    if (tid < 128) {
        int ti = tid >> 6, bi = tid & 63;
        int t = t0 + ti, b = b0 + bi;
        float s = 0.f, sk[K_];
        #pragma unroll
        for (int k = 0; k < K_; ++k) {
            int tau = t - (K_ - 1) + k;
            float d = (tau >= 0) ? dis[tau * B_ + b] : 0.f;
            s += d; sk[k] = s;
        }
        float m = sk[0];
        #pragma unroll
        for (int k = 1; k < K_; ++k) m = fmaxf(m, sk[k]);
        float sum = 0.f;
        #pragma unroll
        for (int k = 0; k < K_; ++k) { sk[k] = __expf(sk[k] - m); sum += sk[k]; }
        float inv = 1.f / sum;
        #pragma unroll
        for (int k = 0; k < K_; ++k) ldl[ti * 640 + bi * 10 + k] = sk[k] * inv;
    }

    const int a_ti = tid >> 8, a_rem = tid & 255;
    const int a_bb = a_rem >> 2, a_half = a_rem & 3;

    auto loadA = [&](int ch, int4& av, bool& valid) {
        int k = ch / 12, hb = (ch % 12) * 32;
        int tau = t0 + a_ti - (K_ - 1) + k;
        valid = (tau >= 0);
        if (valid)
            av = *(const int4*)(hbf + ((size_t)tau * B_ + b0 + a_bb) * H_ + hb + a_half * 8);
    };
    auto loadB = [&](int ch, int4 bv[3]) {
        #pragma unroll
        for (int q = 0; q < 3; ++q) {
            int idx = q * 512 + tid;
            int row = idx >> 2, half = idx & 3;
            bv[q] = *(const int4*)(Wg + (size_t)row * 3840 + ch * 32 + half * 8);
        }
    };
    auto writeA = [&](int buf, int ch, int4 av, bool valid) {
        int k = ch / 12;
        int4 pk = make_int4(0, 0, 0, 0);
        if (valid) {
            float l = ldl[a_ti * 640 + a_bb * 10 + k];
            unsigned vv[4] = {(unsigned)av.x, (unsigned)av.y, (unsigned)av.z, (unsigned)av.w};
            unsigned o[4];
            #pragma unroll
            for (int q = 0; q < 4; ++q) {
                float flo = __uint_as_float(vv[q] << 16) * l;
                float fhi = __uint_as_float(vv[q] & 0xffff0000u) * l;
                o[q] = (unsigned)f2bf(flo) | ((unsigned)f2bf(fhi) << 16);
            }
            pk = make_int4((int)o[0], (int)o[1], (int)o[2], (int)o[3]);
        }
        *(int4*)&AlB[buf * 5120 + a_ti * 2560 + a_bb * 40 + a_half * 8] = pk;
    };
    auto writeB = [&](int buf, const int4 bv[3]) {
        #pragma unroll
        for (int q = 0; q < 3; ++q) {
            int idx = q * 512 + tid;
            int row = idx >> 2, half = idx & 3;
            *(int4*)&BlB[buf * 15360 + row * 40 + half * 8] = bv[q];
        }
    };

    // ---- pipelined prologue ----
    int4 avW; bool avWv; int4 bvW[3];       // chunk to WRITE this iter (ch+1)
    int4 avF; bool avFv; int4 bvF[3];       // chunk in FLIGHT (ch+2)
    loadA(0, avW, avWv); loadB(0, bvW);
    __syncthreads();                        // ldl ready
    writeA(0, 0, avW, avWv); writeB(0, bvW);
    loadA(1, avW, avWv); loadB(1, bvW);
    loadA(2, avF, avFv); loadB(2, bvF);
    __syncthreads();                        // buf0 visible

    f32x4 acc[2][2][6] = {};
    for (int ch = 0; ch < 120; ++ch) {
        int cur = ch & 1;
        // MFMA on buf[cur]
        bf16x8 af[2][2];
        #pragma unroll
        for (int ti = 0; ti < 2; ++ti)
            #pragma unroll
            for (int mi = 0; mi < 2; ++mi)
                af[ti][mi] = *(const bf16x8*)&AlB[cur * 5120 + ti * 2560
                    + (mh * 32 + mi * 16 + (lane & 15)) * 40 + (lane >> 4) * 8];
        #pragma unroll
        for (int ni = 0; ni < 6; ++ni) {
            bf16x8 bfv = *(const bf16x8*)&BlB[cur * 15360
                + (nq * 96 + ni * 16 + (lane & 15)) * 40 + (lane >> 4) * 8];
            #pragma unroll
            for (int ti = 0; ti < 2; ++ti)
                #pragma unroll
                for (int mi = 0; mi < 2; ++mi)
                    acc[ti][mi][ni] = __builtin_amdgcn_mfma_f32_16x16x32_bf16(
                        af[ti][mi], bfv, acc[ti][mi][ni], 0, 0, 0);
        }
        // write chunk ch+1 into buf[cur^1] BEFORE the barrier
        if (ch + 1 < 120) { writeA(cur ^ 1, ch + 1, avW, avWv); writeB(cur ^ 1, bvW); }
        // rotate: W <- F; issue chunk ch+3
        avW = avF; avWv = avFv;
        bvW[0] = bvF[0]; bvW[1] = bvF[1]; bvW[2] = bvF[2];
        if (ch + 3 < 120) { loadA(ch + 3, avF, avFv); loadB(ch + 3, bvF); }
        __syncthreads();
    }

    // ---- per-t: hbar -> u -> theme -> combine ----
    #pragma unroll
    for (int ti = 0; ti < 2; ++ti) {
        const int t = t0 + ti;
        for (int idx = tid; idx < 3072; idx += 512) {
            int bb = idx / 48, h8 = idx % 48;
            float s[8] = {};
            #pragma unroll
            for (int k = 0; k < K_; ++k) {
                int tau = t - (K_ - 1) + k;
                if (tau >= 0) {
                    int4 v = *(const int4*)(hbf + ((size_t)tau * B_ + b0 + bb) * H_ + h8 * 8);
                    float l = ldl[ti * 640 + bb * 10 + k];
                    unsigned vv[4] = {(unsigned)v.x, (unsigned)v.y, (unsigned)v.z, (unsigned)v.w};
                    #pragma unroll
                    for (int q = 0; q < 4; ++q) {
                        s[2 * q]     = fmaf(__uint_as_float(vv[q] << 16), l, s[2 * q]);
                        s[2 * q + 1] = fmaf(__uint_as_float(vv[q] & 0xffff0000u), l, s[2 * q + 1]);
                    }
                }
            }
            unsigned o[4];
            #pragma unroll
            for (int q = 0; q < 4; ++q)
                o[q] = (unsigned)f2bf(s[2 * q] * 0.1f) | ((unsigned)f2bf(s[2 * q + 1] * 0.1f) << 16);
            *(int4*)&hbarL[bb * 400 + h8 * 8] = make_int4((int)o[0], (int)o[1], (int)o[2], (int)o[3]);
        }
        __syncthreads();

        if (wave < 4) {
            f32x4 uacc[4] = {};
            for (int kc = 0; kc < 12; ++kc) {
                bf16x8 a = *(const bf16x8*)&hbarL[(wave * 16 + (lane & 15)) * 400
                                                  + kc * 32 + (lane >> 4) * 8];
                #pragma unroll
                for (int ni = 0; ni < 4; ++ni) {
                    bf16x8 wb = *(const bf16x8*)(WsT + (size_t)(ni * 16 + (lane & 15)) * H_
                                                 + kc * 32 + (lane >> 4) * 8);
                    uacc[ni] = __builtin_amdgcn_mfma_f32_16x16x32_bf16(a, wb, uacc[ni], 0, 0, 0);
                }
            }
            #pragma unroll
            for (int ni = 0; ni < 4; ++ni) {
                float bsv = bs[ni * 16 + (lane & 15)];
                #pragma unroll
                for (int r = 0; r < 4; ++r)
                    uL[(wave * 16 + (lane >> 4) * 4 + r) * 72 + ni * 16 + (lane & 15)] =
                        f2bf(fmaxf(uacc[ni][r] + bsv, 0.f));
            }
        }
        __syncthreads();

        #pragma unroll
        for (int half = 0; half < 2; ++half) {
            f32x4 tacc[2][3] = {};
            #pragma unroll
            for (int kc = 0; kc < 2; ++kc) {
                bf16x8 ua[2];
                #pragma unroll
                for (int mi = 0; mi < 2; ++mi)
                    ua[mi] = *(const bf16x8*)&uL[(mh * 32 + mi * 16 + (lane & 15)) * 72
                                                 + kc * 32 + (lane >> 4) * 8];
                #pragma unroll
                for (int n3 = 0; n3 < 3; ++n3) {
                    int ni = half * 3 + n3;
                    bf16x8 wb = *(const bf16x8*)(WrsT
                        + (size_t)(nq * 96 + ni * 16 + (lane & 15)) * HS_
                        + kc * 32 + (lane >> 4) * 8);
                    #pragma unroll
                    for (int mi = 0; mi < 2; ++mi)
                        tacc[mi][n3] = __builtin_amdgcn_mfma_f32_16x16x32_bf16(
                            ua[mi], wb, tacc[mi][n3], 0, 0, 0);
                }
            }
            #pragma unroll
            for (int mi = 0; mi < 2; ++mi) {
                #pragma unroll
                for (int n3 = 0; n3 < 3; ++n3) {
                    int ni = half * 3 + n3;
                    int o = nq * 96 + ni * 16 + (lane & 15);
                    float brsv = brs[o], bcv = bc[o];
                    int brow0 = b0 + mh * 32 + mi * 16 + ((lane >> 4) << 2);
                    #pragma unroll
                    for (int r = 0; r < 4; ++r) {
                        float th = sig_fast(tacc[mi][n3][r] + brsv);
                        float cv = acc[ti][mi][ni][r] + bcv;
                        float hv = bf2f(hbf[((size_t)t * B_ + brow0 + r) * H_ + o]);
                        out_part[((size_t)(brow0 + r) * T_ + t) * H_ + o] = hv + th * cv;
                    }
                }
            }
        }
        __syncthreads();
    }
}

// ---------------- last_output gather ----------------
__global__ void k_last(const int* __restrict__ len_i, const float* __restrict__ out_part,
                       float* __restrict__ last)
{
    int b = blockIdx.x, tid = threadIdx.x;
    bool is64 = (len_i[1] == 0);
    long long v = is64 ? ((const long long*)len_i)[b] : (long long)len_i[b];
    int idx = (int)v;
    idx = max(1, min(T_, idx)) - 1;
    last[(size_t)b * H_ + tid] = out_part[((size_t)b * T_ + idx) * H_ + tid];
}

extern "C" void kernel_launch(void* const* d_in, const int* in_sizes, int n_in,
                              void* d_out, int out_size, void* d_ws, size_t ws_size,
                              hipStream_t stream) {
    const float* x   = (const float*)d_in[0];
    const int*   len = (const int*)d_in[1];
    const float* Wk  = (const float*)d_in[2];
    const float* bk  = (const float*)d_in[3];
    const float* Wr  = (const float*)d_in[4];
    const float* br  = (const float*)d_in[5];
    const float* Ws  = (const float*)d_in[6];
    const float* bs  = (const float*)d_in[7];
    const float* Wrs = (const float*)d_in[8];
    const float* brs = (const float*)d_in[9];
    const float* Wc  = (const float*)d_in[10];
    const float* bc  = (const float*)d_in[11];

    float* out      = (float*)d_out;
    float* last     = out;
    float* out_part = out + (size_t)B_ * H_;

    // workspace layout (bytes), total ~90 MB
    char* p = (char*)d_ws;
    float*          dis    = (float*)p;          p += (size_t)T_ * B_ * 4;
    unsigned short* xA     = (unsigned short*)p; p += (size_t)T_ * B_ * D_ * 2;
    unsigned short* WfragG = (unsigned short*)p; p += (size_t)NMEM * NKC * NFR * 64 * 8 * 2;
    float*          biasP  = (float*)p;          p += (size_t)NMEM * PCOLS * 4;
    unsigned short* hbf    = (unsigned short*)p; p += (size_t)T_ * B_ * H_ * 2;
    unsigned short* Wg     = (unsigned short*)p; p += (size_t)H_ * K_ * H_ * 2;
    unsigned short* WsT    = (unsigned short*)p; p += (size_t)HS_ * H_ * 2;
    unsigned short* WrsT   = (unsigned short*)p; p += (size_t)H_ * HS_ * 2;

    k_xa  <<<dim3(T_, 4), 256, 0, stream>>>(x, xA);
    k_prep<<<8567, 256, 0, stream>>>(Wk, bk, Wr, br, Ws, Wrs, Wc,
                                     hbf, WfragG, Wg, WsT, WrsT, biasP);

    hipFuncSetAttribute((const void*)k_serial,
                        hipFuncAttributeMaxDynamicSharedMemorySize, LDS_BYTES);
    hipFuncSetAttribute((const void*)k_post,
                        hipFuncAttributeMaxDynamicSharedMemorySize, POST_LDS);

    k_serial<<<NGRP * NMEM, 512, LDS_BYTES, stream>>>(xA, WfragG, biasP, hbf, dis);
    k_post <<<dim3(4, 128), 512, POST_LDS, stream>>>(hbf, dis, Wg, WsT, WrsT, bs, brs, bc, out_part);
    k_last <<<B_, H_, 0, stream>>>(len, out_part, last);
}

// Round 16
// 1502.892 us; speedup vs baseline: 1.1197x; 1.1197x over previous
//
#include <hip/hip_runtime.h>
#include <hip/hip_bf16.h>
#include <cstddef>

// Problem constants
#define B_  256
#define T_  256
#define D_  256
#define H_  384
#define G_  1542
#define L_  3
#define CH_ 128
#define K_  10
#define HS_ 64

// Serial-phase geometry: 16 groups (16 b each) x 16 members (24 ch, 102 cols -> 7 frags)
#define NGRP 16
#define NMEM 16
#define GW   16
#define CPM  24
#define NFR  7
#define PCOLS 112
#define XOLP 114
#define NKC  20
// k_serial LDS layout (bytes)
#define W_LDS    (NKC * NFR * 64 * 8 * 2)   // 143360
#define BIAS_OFF W_LDS
#define UNI_OFF  (W_LDS + 512)              // union: stage 12 slots (12288) / xol (7296)
#define LDS_BYTES (UNI_OFF + 12288)         // 156160

// k_post LDS (dynamic), t-tile = 2: ldl 5120 | A dbuf 40960 | B dbuf 61440 -> 107520
#define POST_LDS 107520

#define SENT 0xFFFFFFFFFFFFFFFFull

using bf16x8 = __attribute__((ext_vector_type(8))) short;
using f32x4  = __attribute__((ext_vector_type(4))) float;
using i32x4  = __attribute__((ext_vector_type(4))) int;
typedef unsigned long long ull_t;

__device__ __forceinline__ float bf2f(unsigned short s) {
    return __uint_as_float(((unsigned)s) << 16);
}
__device__ __forceinline__ unsigned short f2bf(float f) {
    unsigned u = __float_as_uint(f);
    return (unsigned short)((u + 0x7fffu + ((u >> 16) & 1u)) >> 16);
}
__device__ __forceinline__ float sig_fast(float x) { return 1.f / (1.f + __expf(-x)); }
__device__ __forceinline__ float tanh_fast(float x) {
    float ax = fabsf(x);
    float t = __expf(-2.f * ax);
    float r = (1.f - t) / (1.f + t);
    return copysignf(r, x);
}
__device__ __forceinline__ ull_t ldA(const ull_t* p) {
    return __hip_atomic_load(p, __ATOMIC_RELAXED, __HIP_MEMORY_SCOPE_AGENT);
}
// non-temporal 16B load (streaming: don't pollute L2 — keeps Wg resident)
__device__ __forceinline__ int4 ldnt16(const void* p) {
    i32x4 v = __builtin_nontemporal_load((const i32x4*)p);
    return make_int4(v.x, v.y, v.z, v.w);
}
// ready iff NO 16-bit field of v equals 0xFFFF (bf16 -NaN sentinel; h in (-1,1) can't encode it)
__device__ __forceinline__ bool rdy(ull_t v) {
    ull_t x = ~v;
    return (((x - 0x0001000100010001ull) & ~x & 0x8000800080008000ull) == 0ull);
}

// packed col -> gate col (or -1 for pad)
__device__ __forceinline__ int gcol_of(int member, int p) {
    if (p < 6) return p;
    if (p < 102) { int q = p - 6; return 6 + (q / CPM) * H_ + member * CPM + (q % CPM); }
    return -1;
}

// ---------------- xA: A-frag-ordered x (bf16), coalesced via LDS ----------------
__global__ __launch_bounds__(256)
void k_xa(const float* __restrict__ x, unsigned short* __restrict__ xA) {
    __shared__ float xl[64][261];
    const int t = blockIdx.x, bq = blockIdx.y;
    const int b0 = bq * 64, tid = threadIdx.x;
    for (int idx = tid; idx < 4096; idx += 256) {
        int row = idx >> 6, c4 = idx & 63;
        float4 v = *(const float4*)(x + ((size_t)(b0 + row) * T_ + t) * D_ + c4 * 4);
        xl[row][c4 * 4 + 0] = v.x; xl[row][c4 * 4 + 1] = v.y;
        xl[row][c4 * 4 + 2] = v.z; xl[row][c4 * 4 + 3] = v.w;
    }
    __syncthreads();
    for (int idx = tid; idx < 2048; idx += 256) {
        int lane = idx & 63, gl = (idx >> 6) & 3, kc = idx >> 8;
        int brow = gl * 16 + (lane & 15);
        int d = kc * 32 + (lane >> 4) * 8;
        unsigned o[4];
        #pragma unroll
        for (int q = 0; q < 4; ++q)
            o[q] = (unsigned)f2bf(xl[brow][d + 2 * q])
                 | ((unsigned)f2bf(xl[brow][d + 2 * q + 1]) << 16);
        int4 pk = make_int4((int)o[0], (int)o[1], (int)o[2], (int)o[3]);
        ((int4*)xA)[(((size_t)t * 8 + kc) * 16 + (bq * 4 + gl)) * 64 + lane] = pk;
    }
}

// ---------------- merged prep: hbf sentinel + wfrag + wg + wst + wrst + bias -------
__global__ __launch_bounds__(256)
void k_prep(const float* __restrict__ Wk, const float* __restrict__ bk,
            const float* __restrict__ Wr, const float* __restrict__ br,
            const float* __restrict__ Ws, const float* __restrict__ Wrs,
            const float* __restrict__ Wc,
            unsigned short* __restrict__ hbf, unsigned short* __restrict__ Wf,
            unsigned short* __restrict__ Wg, unsigned short* __restrict__ WsT,
            unsigned short* __restrict__ WrsT, float* __restrict__ biasP)
{
    const int bid = blockIdx.x, tid = threadIdx.x;
    if (bid < 2048) {
        ull_t* hb = (ull_t*)hbf;
        int base = bid * 256 + tid;
        #pragma unroll
        for (int j = 0; j < 12; ++j)
            __hip_atomic_store(hb + base + j * 524288, SENT,
                               __ATOMIC_RELAXED, __HIP_MEMORY_SCOPE_AGENT);
    } else if (bid < 2608) {
        int idx = (bid - 2048) * 256 + tid;          // < 143360
        int lane = idx & 63;
        int ni   = (idx >> 6) % NFR;
        int kc   = (idx / (64 * NFR)) % NKC;
        int member = idx / (64 * NFR * NKC);
        int p = ni * 16 + (lane & 15);
        int g = gcol_of(member, p);
        unsigned short out[8];
        #pragma unroll
        for (int j = 0; j < 8; ++j) {
            int k = kc * 32 + (lane >> 4) * 8 + j;
            float v = 0.f;
            if (g >= 0) v = (k < 256) ? Wk[(size_t)k * G_ + g] : Wr[(size_t)(k - 256) * G_ + g];
            out[j] = f2bf(v);
        }
        int4 pk;
        pk.x = (unsigned)out[0] | ((unsigned)out[1] << 16);
        pk.y = (unsigned)out[2] | ((unsigned)out[3] << 16);
        pk.z = (unsigned)out[4] | ((unsigned)out[5] << 16);
        pk.w = (unsigned)out[6] | ((unsigned)out[7] << 16);
        ((int4*)Wf)[idx] = pk;
    } else if (bid < 8368) {
        int idx = (bid - 2608) * 256 + tid;          // < 1474560
        int o = idx / (K_ * H_);
        int rem = idx % (K_ * H_);
        int k = rem / H_, h = rem % H_;
        Wg[idx] = f2bf(Wc[((size_t)o * H_ + h) * K_ + k]);
    } else if (bid < 8464) {
        int idx = (bid - 8368) * 256 + tid;          // < 24576
        int jj = idx / H_, k = idx % H_;
        WsT[idx] = f2bf(Ws[(size_t)k * HS_ + jj]);
    } else if (bid < 8560) {
        int idx = (bid - 8464) * 256 + tid;          // < 24576
        int o = idx / HS_, jj = idx % HS_;
        WrsT[idx] = f2bf(Wrs[(size_t)jj * H_ + o]);
    } else {
        int idx = (bid - 8560) * 256 + tid;
        if (idx < NMEM * PCOLS) {
            int member = idx / PCOLS, p = idx % PCOLS;
            int g = gcol_of(member, p);
            biasP[idx] = (g >= 0)
                ? bk[g] + br[g] + Wk[(size_t)256 * G_ + g] + Wr[(size_t)384 * G_ + g] : 0.f;
        }
    }
}

// ---------------- persistent serial recurrence (direct-publish sentinel protocol) ---
__global__ __launch_bounds__(512, 1)
void k_serial(const unsigned short* __restrict__ xA, const unsigned short* __restrict__ Wf,
              const float* __restrict__ biasP,
              unsigned short* __restrict__ hbf, float* __restrict__ dis)
{
    extern __shared__ char lds_raw[];
    unsigned short* Wl = (unsigned short*)lds_raw;
    float* biasL = (float*)(lds_raw + BIAS_OFF);
    char* uni = lds_raw + UNI_OFF;
    float* xol = (float*)uni;                                   // 16 x 114 f32 (< 12288)
    int4* stage4 = (int4*)uni;                                  // 12 kc x 64 lanes x 16B
    const bf16x8* stage = (const bf16x8*)uni;

    const int tid = threadIdx.x;
    const int lane = tid & 63, wave = tid >> 6;
    const int group = blockIdx.x & 15, member = blockIdx.x >> 4;
    const int b0 = group * GW;
    const int ni = wave;
    const bool domm = (wave < NFR);

    {
        const int4* src = (const int4*)(Wf + (size_t)member * (NKC * NFR * 64 * 8));
        for (int i = tid; i < W_LDS / 16; i += 512) ((int4*)Wl)[i] = src[i];
        if (tid < PCOLS) biasL[tid] = biasP[member * PCOLS + tid];
    }
    __syncthreads();

    const float bias_a = domm ? biasL[ni * 16 + (lane & 15)] : 0.f;

    const bool hasS = (tid < 384);
    const int skcl = tid >> 6, sln = tid & 63;
    const int stA = skcl * 64 + sln;
    const int stB = (skcl + 6) * 64 + sln;
    const unsigned short* src0 =
        hbf + (size_t)(b0 + (sln & 15)) * H_ + skcl * 32 + (sln >> 4) * 8;

    float c_r0 = 0.f;

    for (int t = 0; t < T_; ++t) {
        bf16x8 xf[8];
        if (domm) {
            #pragma unroll
            for (int kc = 0; kc < 8; ++kc)
                xf[kc] = *((const bf16x8*)(xA
                    + (((size_t)t * 8 + kc) * 16 + group) * 512 + lane * 8));
        }

        // dual accumulator chains (break MFMA dep latency)
        f32x4 accA = f32x4{bias_a, bias_a, bias_a, bias_a};
        f32x4 accB = f32x4{0.f, 0.f, 0.f, 0.f};

        if (t > 0) {
            const size_t toff = (size_t)(t - 1) * B_ * H_;
            const ull_t* pA = (const ull_t*)(src0 + toff);
            const ull_t* pB = (const ull_t*)(src0 + toff + 192);
            ull_t v0 = SENT, v1 = SENT, v2 = SENT, v3 = SENT;
            if (hasS) { v0 = ldA(pA); v1 = ldA(pA + 1); v2 = ldA(pB); v3 = ldA(pB + 1); }

            if (domm) {
                #pragma unroll
                for (int kc = 0; kc < 8; ++kc) {
                    bf16x8 w0 = ((const bf16x8*)Wl)[(kc * NFR + ni) * 64 + lane];
                    if (kc & 1)
                        accB = __builtin_amdgcn_mfma_f32_16x16x32_bf16(xf[kc], w0, accB, 0, 0, 0);
                    else
                        accA = __builtin_amdgcn_mfma_f32_16x16x32_bf16(xf[kc], w0, accA, 0, 0, 0);
                }
            }

            if (hasS) {
                while (!(rdy(v0) && rdy(v1) && rdy(v2) && rdy(v3))) {
                    v0 = ldA(pA); v1 = ldA(pA + 1); v2 = ldA(pB); v3 = ldA(pB + 1);
                }
                stage4[stA] = make_int4((int)(v0 & 0xffffffffu), (int)(v0 >> 32),
                                        (int)(v1 & 0xffffffffu), (int)(v1 >> 32));
                stage4[stB] = make_int4((int)(v2 & 0xffffffffu), (int)(v2 >> 32),
                                        (int)(v3 & 0xffffffffu), (int)(v3 >> 32));
            }
            __syncthreads();                                    // S1: stage ready
            if (domm) {
                #pragma unroll
                for (int kcl = 0; kcl < 12; ++kcl) {
                    bf16x8 a0 = stage[kcl * 64 + lane];
                    bf16x8 w0 = ((const bf16x8*)Wl)[((8 + kcl) * NFR + ni) * 64 + lane];
                    if (kcl & 1)
                        accB = __builtin_amdgcn_mfma_f32_16x16x32_bf16(a0, w0, accB, 0, 0, 0);
                    else
                        accA = __builtin_amdgcn_mfma_f32_16x16x32_bf16(a0, w0, accA, 0, 0, 0);
                }
            }
            __syncthreads();                                    // S2: stage dead
        } else {
            if (domm) {
                #pragma unroll
                for (int kc = 0; kc < 8; ++kc) {
                    bf16x8 w0 = ((const bf16x8*)Wl)[(kc * NFR + ni) * 64 + lane];
                    if (kc & 1)
                        accB = __builtin_amdgcn_mfma_f32_16x16x32_bf16(xf[kc], w0, accB, 0, 0, 0);
                    else
                        accA = __builtin_amdgcn_mfma_f32_16x16x32_bf16(xf[kc], w0, accA, 0, 0, 0);
                }
            }
        }

        if (domm) {
            #pragma unroll
            for (int r = 0; r < 4; ++r)
                xol[((lane >> 4) * 4 + r) * XOLP + ni * 16 + (lane & 15)] = accA[r] + accB[r];
        }
        __syncthreads();                                        // S3: xol ready

        // ---- gates: 384 items; DIRECT publication (paired u32 agent stores) ----
        if (tid < 384) {
            int b = tid & 15, ch = tid >> 4;
            const float* row = xol + b * XOLP;
            float z0 = row[0], z1 = row[1], z2 = row[2];
            float z3 = row[3], z4 = row[4], z5 = row[5];
            float m1 = fmaxf(fmaxf(z0, z1), z2);
            float e0 = __expf(z0 - m1), e1 = __expf(z1 - m1), e2 = __expf(z2 - m1);
            float inv1 = 1.f / (e0 + e1 + e2);
            float fm0 = e0 * inv1, fm1 = (e0 + e1) * inv1;
            float m2 = fmaxf(fmaxf(z3, z4), z5);
            float f3 = __expf(z3 - m2), f4 = __expf(z4 - m2), f5 = __expf(z5 - m2);
            float inv2 = 1.f / (f3 + f4 + f5);
            float im1 = (f4 + f5) * inv2, im2 = f5 * inv2;

            int hh = member * CPM + ch;
            int l = hh >> 7;
            float fm = (l == 0) ? fm0 : (l == 1) ? fm1 : 1.f;
            float im = (l == 0) ? 1.f : (l == 1) ? im1 : im2;

            float fg = sig_fast(row[6 + ch]);
            float ig = sig_fast(row[6 + CPM + ch]);
            float og = sig_fast(row[6 + 2 * CPM + ch]);
            float ci = tanh_fast(row[6 + 3 * CPM + ch]);

            float ov = fm * im;
            float cn = ov * (fg * c_r0 + ig * ci) + (fm - ov) * c_r0 + (im - ov) * ci;
            float hn = og * tanh_fast(cn);
            c_r0 = cn;

            unsigned hpk = (unsigned)f2bf(hn);
            unsigned partner = (unsigned)__shfl((int)hpk, (lane + 16) & 63);
            if (!(ch & 1)) {
                unsigned word = hpk | (partner << 16);
                __hip_atomic_store(
                    (unsigned*)(hbf + ((size_t)t * B_ + b0 + b) * H_ + hh),
                    word, __ATOMIC_RELAXED, __HIP_MEMORY_SCOPE_AGENT);
            }
            if (member == 0 && ch == 0)
                dis[t * B_ + b0 + b] = 1.f - (fm0 + fm1 + 1.f) * (1.f / 3.f);
        }
        // no trailing sync: consumers spin on the data itself
    }
}

// ---------------- fused post: TT=2 conv (dbuf, round-14 structure) + NT streaming ---
__global__ __launch_bounds__(512, 1)
void k_post(const unsigned short* __restrict__ hbf, const float* __restrict__ dis,
            const unsigned short* __restrict__ Wg,
            const unsigned short* __restrict__ WsT, const unsigned short* __restrict__ WrsT,
            const float* __restrict__ bs, const float* __restrict__ brs,
            const float* __restrict__ bc, float* __restrict__ out_part)
{
    extern __shared__ char plds[];
    float* ldl = (float*)plds;                                   // [2][64][10] 5120
    unsigned short* AlB = (unsigned short*)(plds + 5120);        // [2][2][64][40] 40960
    unsigned short* BlB = (unsigned short*)(plds + 46080);       // [2][384][40] 61440
    unsigned short* hbarL = (unsigned short*)(plds + 5120);      // [64][400] (post-conv)
    unsigned short* uL = (unsigned short*)(plds + 56320);        // [64][72]

    const int b0 = blockIdx.x * 64;
    const int t0 = blockIdx.y * 2;
    const int tid = threadIdx.x;
    const int wave = tid >> 6, lane = tid & 63;
    const int mh = wave >> 2, nq = wave & 3;

    if (tid < 128) {
        int ti = tid >> 6, bi = tid & 63;
        int t = t0 + ti, b = b0 + bi;
        float s = 0.f, sk[K_];
        #pragma unroll
        for (int k = 0; k < K_; ++k) {
            int tau = t - (K_ - 1) + k;
            float d = (tau >= 0) ? dis[tau * B_ + b] : 0.f;
            s += d; sk[k] = s;
        }
        float m = sk[0];
        #pragma unroll
        for (int k = 1; k < K_; ++k) m = fmaxf(m, sk[k]);
        float sum = 0.f;
        #pragma unroll
        for (int k = 0; k < K_; ++k) { sk[k] = __expf(sk[k] - m); sum += sk[k]; }
        float inv = 1.f / sum;
        #pragma unroll
        for (int k = 0; k < K_; ++k) ldl[ti * 640 + bi * 10 + k] = sk[k] * inv;
    }

    const int a_ti = tid >> 8, a_rem = tid & 255;
    const int a_bb = a_rem >> 2, a_half = a_rem & 3;

    auto loadA = [&](int ch, int4& av, bool& valid) {
        int k = ch / 12, hb = (ch % 12) * 32;
        int tau = t0 + a_ti - (K_ - 1) + k;
        valid = (tau >= 0);
        if (valid)
            av = ldnt16(hbf + ((size_t)tau * B_ + b0 + a_bb) * H_ + hb + a_half * 8);
    };
    auto loadB = [&](int ch, int4 bv[3]) {
        #pragma unroll
        for (int q = 0; q < 3; ++q) {
            int idx = q * 512 + tid;
            int row = idx >> 2, half = idx & 3;
            bv[q] = *(const int4*)(Wg + (size_t)row * 3840 + ch * 32 + half * 8);
        }
    };
    auto writeA = [&](int buf, int ch, int4 av, bool valid) {
        int k = ch / 12;
        int4 pk = make_int4(0, 0, 0, 0);
        if (valid) {
            float l = ldl[a_ti * 640 + a_bb * 10 + k];
            unsigned vv[4] = {(unsigned)av.x, (unsigned)av.y, (unsigned)av.z, (unsigned)av.w};
            unsigned o[4];
            #pragma unroll
            for (int q = 0; q < 4; ++q) {
                float flo = __uint_as_float(vv[q] << 16) * l;
                float fhi = __uint_as_float(vv[q] & 0xffff0000u) * l;
                o[q] = (unsigned)f2bf(flo) | ((unsigned)f2bf(fhi) << 16);
            }
            pk = make_int4((int)o[0], (int)o[1], (int)o[2], (int)o[3]);
        }
        *(int4*)&AlB[buf * 5120 + a_ti * 2560 + a_bb * 40 + a_half * 8] = pk;
    };
    auto writeB = [&](int buf, const int4 bv[3]) {
        #pragma unroll
        for (int q = 0; q < 3; ++q) {
            int idx = q * 512 + tid;
            int row = idx >> 2, half = idx & 3;
            *(int4*)&BlB[buf * 15360 + row * 40 + half * 8] = bv[q];
        }
    };

    int4 av; bool avalid; int4 bv[3];
    loadA(0, av, avalid); loadB(0, bv);
    __syncthreads();                    // ldl ready
    writeA(0, 0, av, avalid); writeB(0, bv);

    f32x4 acc[2][2][6] = {};
    for (int ch = 0; ch < 120; ++ch) {
        int cur = ch & 1;
        bool more = (ch + 1 < 120);
        if (more) { loadA(ch + 1, av, avalid); loadB(ch + 1, bv); }
        __syncthreads();
        if (more) { writeA(cur ^ 1, ch + 1, av, avalid); writeB(cur ^ 1, bv); }

        bf16x8 af[2][2];
        #pragma unroll
        for (int ti = 0; ti < 2; ++ti)
            #pragma unroll
            for (int mi = 0; mi < 2; ++mi)
                af[ti][mi] = *(const bf16x8*)&AlB[cur * 5120 + ti * 2560
                    + (mh * 32 + mi * 16 + (lane & 15)) * 40 + (lane >> 4) * 8];
        #pragma unroll
        for (int ni = 0; ni < 6; ++ni) {
            bf16x8 bfv = *(const bf16x8*)&BlB[cur * 15360
                + (nq * 96 + ni * 16 + (lane & 15)) * 40 + (lane >> 4) * 8];
            #pragma unroll
            for (int ti = 0; ti < 2; ++ti)
                #pragma unroll
                for (int mi = 0; mi < 2; ++mi)
                    acc[ti][mi][ni] = __builtin_amdgcn_mfma_f32_16x16x32_bf16(
                        af[ti][mi], bfv, acc[ti][mi][ni], 0, 0, 0);
        }
    }
    __syncthreads();

    #pragma unroll
    for (int ti = 0; ti < 2; ++ti) {
        const int t = t0 + ti;
        for (int idx = tid; idx < 3072; idx += 512) {
            int bb = idx / 48, h8 = idx % 48;
            float s[8] = {};
            #pragma unroll
            for (int k = 0; k < K_; ++k) {
                int tau = t - (K_ - 1) + k;
                if (tau >= 0) {
                    int4 v = ldnt16(hbf + ((size_t)tau * B_ + b0 + bb) * H_ + h8 * 8);
                    float l = ldl[ti * 640 + bb * 10 + k];
                    unsigned vv[4] = {(unsigned)v.x, (unsigned)v.y, (unsigned)v.z, (unsigned)v.w};
                    #pragma unroll
                    for (int q = 0; q < 4; ++q) {
                        s[2 * q]     = fmaf(__uint_as_float(vv[q] << 16), l, s[2 * q]);
                        s[2 * q + 1] = fmaf(__uint_as_float(vv[q] & 0xffff0000u), l, s[2 * q + 1]);
                    }
                }
            }
            unsigned o[4];
            #pragma unroll
            for (int q = 0; q < 4; ++q)
                o[q] = (unsigned)f2bf(s[2 * q] * 0.1f) | ((unsigned)f2bf(s[2 * q + 1] * 0.1f) << 16);
            *(int4*)&hbarL[bb * 400 + h8 * 8] = make_int4((int)o[0], (int)o[1], (int)o[2], (int)o[3]);
        }
        __syncthreads();

        if (wave < 4) {
            f32x4 uacc[4] = {};
            for (int kc = 0; kc < 12; ++kc) {
                bf16x8 a = *(const bf16x8*)&hbarL[(wave * 16 + (lane & 15)) * 400
                                                  + kc * 32 + (lane >> 4) * 8];
                #pragma unroll
                for (int ni = 0; ni < 4; ++ni) {
                    bf16x8 wb = *(const bf16x8*)(WsT + (size_t)(ni * 16 + (lane & 15)) * H_
                                                 + kc * 32 + (lane >> 4) * 8);
                    uacc[ni] = __builtin_amdgcn_mfma_f32_16x16x32_bf16(a, wb, uacc[ni], 0, 0, 0);
                }
            }
            #pragma unroll
            for (int ni = 0; ni < 4; ++ni) {
                float bsv = bs[ni * 16 + (lane & 15)];
                #pragma unroll
                for (int r = 0; r < 4; ++r)
                    uL[(wave * 16 + (lane >> 4) * 4 + r) * 72 + ni * 16 + (lane & 15)] =
                        f2bf(fmaxf(uacc[ni][r] + bsv, 0.f));
            }
        }
        __syncthreads();

        #pragma unroll
        for (int half = 0; half < 2; ++half) {
            f32x4 tacc[2][3] = {};
            #pragma unroll
            for (int kc = 0; kc < 2; ++kc) {
                bf16x8 ua[2];
                #pragma unroll
                for (int mi = 0; mi < 2; ++mi)
                    ua[mi] = *(const bf16x8*)&uL[(mh * 32 + mi * 16 + (lane & 15)) * 72
                                                 + kc * 32 + (lane >> 4) * 8];
                #pragma unroll
                for (int n3 = 0; n3 < 3; ++n3) {
                    int ni = half * 3 + n3;
                    bf16x8 wb = *(const bf16x8*)(WrsT
                        + (size_t)(nq * 96 + ni * 16 + (lane & 15)) * HS_
                        + kc * 32 + (lane >> 4) * 8);
                    #pragma unroll
                    for (int mi = 0; mi < 2; ++mi)
                        tacc[mi][n3] = __builtin_amdgcn_mfma_f32_16x16x32_bf16(
                            ua[mi], wb, tacc[mi][n3], 0, 0, 0);
                }
            }
            #pragma unroll
            for (int mi = 0; mi < 2; ++mi) {
                #pragma unroll
                for (int n3 = 0; n3 < 3; ++n3) {
                    int ni = half * 3 + n3;
                    int o = nq * 96 + ni * 16 + (lane & 15);
                    float brsv = brs[o], bcv = bc[o];
                    int brow0 = b0 + mh * 32 + mi * 16 + ((lane >> 4) << 2);
                    #pragma unroll
                    for (int r = 0; r < 4; ++r) {
                        float th = sig_fast(tacc[mi][n3][r] + brsv);
                        float cv = acc[ti][mi][ni][r] + bcv;
                        unsigned short hu = __builtin_nontemporal_load(
                            hbf + ((size_t)t * B_ + brow0 + r) * H_ + o);
                        float hv = bf2f(hu);
                        __builtin_nontemporal_store(hv + th * cv,
                            out_part + ((size_t)(brow0 + r) * T_ + t) * H_ + o);
                    }
                }
            }
        }
        __syncthreads();
    }
}

// ---------------- last_output gather ----------------
__global__ void k_last(const int* __restrict__ len_i, const float* __restrict__ out_part,
                       float* __restrict__ last)
{
    int b = blockIdx.x, tid = threadIdx.x;
    bool is64 = (len_i[1] == 0);
    long long v = is64 ? ((const long long*)len_i)[b] : (long long)len_i[b];
    int idx = (int)v;
    idx = max(1, min(T_, idx)) - 1;
    last[(size_t)b * H_ + tid] = out_part[((size_t)b * T_ + idx) * H_ + tid];
}

extern "C" void kernel_launch(void* const* d_in, const int* in_sizes, int n_in,
                              void* d_out, int out_size, void* d_ws, size_t ws_size,
                              hipStream_t stream) {
    const float* x   = (const float*)d_in[0];
    const int*   len = (const int*)d_in[1];
    const float* Wk  = (const float*)d_in[2];
    const float* bk  = (const float*)d_in[3];
    const float* Wr  = (const float*)d_in[4];
    const float* br  = (const float*)d_in[5];
    const float* Ws  = (const float*)d_in[6];
    const float* bs  = (const float*)d_in[7];
    const float* Wrs = (const float*)d_in[8];
    const float* brs = (const float*)d_in[9];
    const float* Wc  = (const float*)d_in[10];
    const float* bc  = (const float*)d_in[11];

    float* out      = (float*)d_out;
    float* last     = out;
    float* out_part = out + (size_t)B_ * H_;

    // workspace layout (bytes), total ~90 MB
    char* p = (char*)d_ws;
    float*          dis    = (float*)p;          p += (size_t)T_ * B_ * 4;
    unsigned short* xA     = (unsigned short*)p; p += (size_t)T_ * B_ * D_ * 2;
    unsigned short* WfragG = (unsigned short*)p; p += (size_t)NMEM * NKC * NFR * 64 * 8 * 2;
    float*          biasP  = (float*)p;          p += (size_t)NMEM * PCOLS * 4;
    unsigned short* hbf    = (unsigned short*)p; p += (size_t)T_ * B_ * H_ * 2;
    unsigned short* Wg     = (unsigned short*)p; p += (size_t)H_ * K_ * H_ * 2;
    unsigned short* WsT    = (unsigned short*)p; p += (size_t)HS_ * H_ * 2;
    unsigned short* WrsT   = (unsigned short*)p; p += (size_t)H_ * HS_ * 2;

    k_xa  <<<dim3(T_, 4), 256, 0, stream>>>(x, xA);
    k_prep<<<8567, 256, 0, stream>>>(Wk, bk, Wr, br, Ws, Wrs, Wc,
                                     hbf, WfragG, Wg, WsT, WrsT, biasP);

    hipFuncSetAttribute((const void*)k_serial,
                        hipFuncAttributeMaxDynamicSharedMemorySize, LDS_BYTES);
    hipFuncSetAttribute((const void*)k_post,
                        hipFuncAttributeMaxDynamicSharedMemorySize, POST_LDS);

    k_serial<<<NGRP * NMEM, 512, LDS_BYTES, stream>>>(xA, WfragG, biasP, hbf, dis);
    k_post <<<dim3(4, 128), 512, POST_LDS, stream>>>(hbf, dis, Wg, WsT, WrsT, bs, brs, bc, out_part);
    k_last <<<B_, H_, 0, stream>>>(len, out_part, last);
}

// Round 17
// 1283.586 us; speedup vs baseline: 1.3110x; 1.1709x over previous
//
#include <hip/hip_runtime.h>
#include <hip/hip_bf16.h>
#include <cstddef>

// Problem constants
#define B_  256
#define T_  256
#define D_  256
#define H_  384
#define G_  1542
#define L_  3
#define CH_ 128
#define K_  10
#define HS_ 64

// Serial-phase geometry: 16 groups (16 b each) x 16 members (24 ch, 102 cols -> 7 frags)
#define NGRP 16
#define NMEM 16
#define GW   16
#define CPM  24
#define NFR  7
#define PCOLS 112
#define XOLP 114
#define NKC  20
// k_serial LDS layout (bytes)
#define W_LDS    (NKC * NFR * 64 * 8 * 2)   // 143360
#define BIAS_OFF W_LDS
#define UNI_OFF  (W_LDS + 512)              // union: stage 12 slots (12288) / xol (7296)
#define LDS_BYTES (UNI_OFF + 12288)         // 156160

// k_post LDS (dynamic), t-tile = 2: ldl 5120 | A dbuf 40960 | B dbuf 61440 -> 107520
#define POST_LDS 107520

#define SENT 0xFFFFFFFFFFFFFFFFull

using bf16x8 = __attribute__((ext_vector_type(8))) short;
using f32x4  = __attribute__((ext_vector_type(4))) float;
typedef unsigned long long ull_t;

__device__ __forceinline__ float bf2f(unsigned short s) {
    return __uint_as_float(((unsigned)s) << 16);
}
__device__ __forceinline__ unsigned short f2bf(float f) {
    unsigned u = __float_as_uint(f);
    return (unsigned short)((u + 0x7fffu + ((u >> 16) & 1u)) >> 16);
}
__device__ __forceinline__ float sig_fast(float x) { return 1.f / (1.f + __expf(-x)); }
__device__ __forceinline__ float tanh_fast(float x) {
    float ax = fabsf(x);
    float t = __expf(-2.f * ax);
    float r = (1.f - t) / (1.f + t);
    return copysignf(r, x);
}
__device__ __forceinline__ ull_t ldA(const ull_t* p) {
    return __hip_atomic_load(p, __ATOMIC_RELAXED, __HIP_MEMORY_SCOPE_AGENT);
}
// ready iff NO 16-bit field of v equals 0xFFFF (bf16 -NaN sentinel; h in (-1,1) can't encode it)
__device__ __forceinline__ bool rdy(ull_t v) {
    ull_t x = ~v;
    return (((x - 0x0001000100010001ull) & ~x & 0x8000800080008000ull) == 0ull);
}

// packed col -> gate col (or -1 for pad)
__device__ __forceinline__ int gcol_of(int member, int p) {
    if (p < 6) return p;
    if (p < 102) { int q = p - 6; return 6 + (q / CPM) * H_ + member * CPM + (q % CPM); }
    return -1;
}

// ---------------- xA: A-frag-ordered x (bf16), coalesced via LDS ----------------
__global__ __launch_bounds__(256)
void k_xa(const float* __restrict__ x, unsigned short* __restrict__ xA) {
    __shared__ float xl[64][261];
    const int t = blockIdx.x, bq = blockIdx.y;
    const int b0 = bq * 64, tid = threadIdx.x;
    for (int idx = tid; idx < 4096; idx += 256) {
        int row = idx >> 6, c4 = idx & 63;
        float4 v = *(const float4*)(x + ((size_t)(b0 + row) * T_ + t) * D_ + c4 * 4);
        xl[row][c4 * 4 + 0] = v.x; xl[row][c4 * 4 + 1] = v.y;
        xl[row][c4 * 4 + 2] = v.z; xl[row][c4 * 4 + 3] = v.w;
    }
    __syncthreads();
    for (int idx = tid; idx < 2048; idx += 256) {
        int lane = idx & 63, gl = (idx >> 6) & 3, kc = idx >> 8;
        int brow = gl * 16 + (lane & 15);
        int d = kc * 32 + (lane >> 4) * 8;
        unsigned o[4];
        #pragma unroll
        for (int q = 0; q < 4; ++q)
            o[q] = (unsigned)f2bf(xl[brow][d + 2 * q])
                 | ((unsigned)f2bf(xl[brow][d + 2 * q + 1]) << 16);
        int4 pk = make_int4((int)o[0], (int)o[1], (int)o[2], (int)o[3]);
        ((int4*)xA)[(((size_t)t * 8 + kc) * 16 + (bq * 4 + gl)) * 64 + lane] = pk;
    }
}

// ---------------- merged prep: hbf sentinel + wfrag + wg + wst + wrst + bias -------
__global__ __launch_bounds__(256)
void k_prep(const float* __restrict__ Wk, const float* __restrict__ bk,
            const float* __restrict__ Wr, const float* __restrict__ br,
            const float* __restrict__ Ws, const float* __restrict__ Wrs,
            const float* __restrict__ Wc,
            unsigned short* __restrict__ hbf, unsigned short* __restrict__ Wf,
            unsigned short* __restrict__ Wg, unsigned short* __restrict__ WsT,
            unsigned short* __restrict__ WrsT, float* __restrict__ biasP)
{
    const int bid = blockIdx.x, tid = threadIdx.x;
    if (bid < 2048) {
        ull_t* hb = (ull_t*)hbf;
        int base = bid * 256 + tid;
        #pragma unroll
        for (int j = 0; j < 12; ++j)
            __hip_atomic_store(hb + base + j * 524288, SENT,
                               __ATOMIC_RELAXED, __HIP_MEMORY_SCOPE_AGENT);
    } else if (bid < 2608) {
        int idx = (bid - 2048) * 256 + tid;          // < 143360
        int lane = idx & 63;
        int ni   = (idx >> 6) % NFR;
        int kc   = (idx / (64 * NFR)) % NKC;
        int member = idx / (64 * NFR * NKC);
        int p = ni * 16 + (lane & 15);
        int g = gcol_of(member, p);
        unsigned short out[8];
        #pragma unroll
        for (int j = 0; j < 8; ++j) {
            int k = kc * 32 + (lane >> 4) * 8 + j;
            float v = 0.f;
            if (g >= 0) v = (k < 256) ? Wk[(size_t)k * G_ + g] : Wr[(size_t)(k - 256) * G_ + g];
            out[j] = f2bf(v);
        }
        int4 pk;
        pk.x = (unsigned)out[0] | ((unsigned)out[1] << 16);
        pk.y = (unsigned)out[2] | ((unsigned)out[3] << 16);
        pk.z = (unsigned)out[4] | ((unsigned)out[5] << 16);
        pk.w = (unsigned)out[6] | ((unsigned)out[7] << 16);
        ((int4*)Wf)[idx] = pk;
    } else if (bid < 8368) {
        int idx = (bid - 2608) * 256 + tid;          // < 1474560
        int o = idx / (K_ * H_);
        int rem = idx % (K_ * H_);
        int k = rem / H_, h = rem % H_;
        Wg[idx] = f2bf(Wc[((size_t)o * H_ + h) * K_ + k]);
    } else if (bid < 8464) {
        int idx = (bid - 8368) * 256 + tid;          // < 24576
        int jj = idx / H_, k = idx % H_;
        WsT[idx] = f2bf(Ws[(size_t)k * HS_ + jj]);
    } else if (bid < 8560) {
        int idx = (bid - 8464) * 256 + tid;          // < 24576
        int o = idx / HS_, jj = idx % HS_;
        WrsT[idx] = f2bf(Wrs[(size_t)jj * H_ + o]);
    } else {
        int idx = (bid - 8560) * 256 + tid;
        if (idx < NMEM * PCOLS) {
            int member = idx / PCOLS, p = idx % PCOLS;
            int g = gcol_of(member, p);
            biasP[idx] = (g >= 0)
                ? bk[g] + br[g] + Wk[(size_t)256 * G_ + g] + Wr[(size_t)384 * G_ + g] : 0.f;
        }
    }
}

// ---------------- persistent serial recurrence (direct-publish sentinel protocol) ---
__global__ __launch_bounds__(512, 1)
void k_serial(const unsigned short* __restrict__ xA, const unsigned short* __restrict__ Wf,
              const float* __restrict__ biasP,
              unsigned short* __restrict__ hbf, float* __restrict__ dis)
{
    extern __shared__ char lds_raw[];
    unsigned short* Wl = (unsigned short*)lds_raw;
    float* biasL = (float*)(lds_raw + BIAS_OFF);
    char* uni = lds_raw + UNI_OFF;
    float* xol = (float*)uni;                                   // 16 x 114 f32 (< 12288)
    int4* stage4 = (int4*)uni;                                  // 12 kc x 64 lanes x 16B
    const bf16x8* stage = (const bf16x8*)uni;

    const int tid = threadIdx.x;
    const int lane = tid & 63, wave = tid >> 6;
    const int group = blockIdx.x & 15, member = blockIdx.x >> 4;
    const int b0 = group * GW;
    const int ni = wave;
    const bool domm = (wave < NFR);

    {
        const int4* src = (const int4*)(Wf + (size_t)member * (NKC * NFR * 64 * 8));
        for (int i = tid; i < W_LDS / 16; i += 512) ((int4*)Wl)[i] = src[i];
        if (tid < PCOLS) biasL[tid] = biasP[member * PCOLS + tid];
    }
    __syncthreads();

    const float bias_a = domm ? biasL[ni * 16 + (lane & 15)] : 0.f;

    const bool hasS = (tid < 384);
    const int skcl = tid >> 6, sln = tid & 63;
    const int stA = skcl * 64 + sln;
    const int stB = (skcl + 6) * 64 + sln;
    const unsigned short* src0 =
        hbf + (size_t)(b0 + (sln & 15)) * H_ + skcl * 32 + (sln >> 4) * 8;

    float c_r0 = 0.f;

    for (int t = 0; t < T_; ++t) {
        bf16x8 xf[8];
        if (domm) {
            #pragma unroll
            for (int kc = 0; kc < 8; ++kc)
                xf[kc] = *((const bf16x8*)(xA
                    + (((size_t)t * 8 + kc) * 16 + group) * 512 + lane * 8));
        }

        // dual accumulator chains (break MFMA dep latency)
        f32x4 accA = f32x4{bias_a, bias_a, bias_a, bias_a};
        f32x4 accB = f32x4{0.f, 0.f, 0.f, 0.f};

        if (t > 0) {
            const size_t toff = (size_t)(t - 1) * B_ * H_;
            const ull_t* pA = (const ull_t*)(src0 + toff);
            const ull_t* pB = (const ull_t*)(src0 + toff + 192);
            ull_t v0 = SENT, v1 = SENT, v2 = SENT, v3 = SENT;
            if (hasS) { v0 = ldA(pA); v1 = ldA(pA + 1); v2 = ldA(pB); v3 = ldA(pB + 1); }

            if (domm) {
                #pragma unroll
                for (int kc = 0; kc < 8; ++kc) {
                    bf16x8 w0 = ((const bf16x8*)Wl)[(kc * NFR + ni) * 64 + lane];
                    if (kc & 1)
                        accB = __builtin_amdgcn_mfma_f32_16x16x32_bf16(xf[kc], w0, accB, 0, 0, 0);
                    else
                        accA = __builtin_amdgcn_mfma_f32_16x16x32_bf16(xf[kc], w0, accA, 0, 0, 0);
                }
            }

            if (hasS) {
                while (!(rdy(v0) && rdy(v1) && rdy(v2) && rdy(v3))) {
                    v0 = ldA(pA); v1 = ldA(pA + 1); v2 = ldA(pB); v3 = ldA(pB + 1);
                }
                stage4[stA] = make_int4((int)(v0 & 0xffffffffu), (int)(v0 >> 32),
                                        (int)(v1 & 0xffffffffu), (int)(v1 >> 32));
                stage4[stB] = make_int4((int)(v2 & 0xffffffffu), (int)(v2 >> 32),
                                        (int)(v3 & 0xffffffffu), (int)(v3 >> 32));
            }
            __syncthreads();                                    // S1: stage ready
            if (domm) {
                #pragma unroll
                for (int kcl = 0; kcl < 12; ++kcl) {
                    bf16x8 a0 = stage[kcl * 64 + lane];
                    bf16x8 w0 = ((const bf16x8*)Wl)[((8 + kcl) * NFR + ni) * 64 + lane];
                    if (kcl & 1)
                        accB = __builtin_amdgcn_mfma_f32_16x16x32_bf16(a0, w0, accB, 0, 0, 0);
                    else
                        accA = __builtin_amdgcn_mfma_f32_16x16x32_bf16(a0, w0, accA, 0, 0, 0);
                }
            }
            __syncthreads();                                    // S2: stage dead
        } else {
            if (domm) {
                #pragma unroll
                for (int kc = 0; kc < 8; ++kc) {
                    bf16x8 w0 = ((const bf16x8*)Wl)[(kc * NFR + ni) * 64 + lane];
                    if (kc & 1)
                        accB = __builtin_amdgcn_mfma_f32_16x16x32_bf16(xf[kc], w0, accB, 0, 0, 0);
                    else
                        accA = __builtin_amdgcn_mfma_f32_16x16x32_bf16(xf[kc], w0, accA, 0, 0, 0);
                }
            }
        }

        if (domm) {
            #pragma unroll
            for (int r = 0; r < 4; ++r)
                xol[((lane >> 4) * 4 + r) * XOLP + ni * 16 + (lane & 15)] = accA[r] + accB[r];
        }
        __syncthreads();                                        // S3: xol ready

        // ---- gates: 384 items; DIRECT publication (paired u32 agent stores) ----
        if (tid < 384) {
            int b = tid & 15, ch = tid >> 4;
            const float* row = xol + b * XOLP;
            float z0 = row[0], z1 = row[1], z2 = row[2];
            float z3 = row[3], z4 = row[4], z5 = row[5];
            float m1 = fmaxf(fmaxf(z0, z1), z2);
            float e0 = __expf(z0 - m1), e1 = __expf(z1 - m1), e2 = __expf(z2 - m1);
            float inv1 = 1.f / (e0 + e1 + e2);
            float fm0 = e0 * inv1, fm1 = (e0 + e1) * inv1;
            float m2 = fmaxf(fmaxf(z3, z4), z5);
            float f3 = __expf(z3 - m2), f4 = __expf(z4 - m2), f5 = __expf(z5 - m2);
            float inv2 = 1.f / (f3 + f4 + f5);
            float im1 = (f4 + f5) * inv2, im2 = f5 * inv2;

            int hh = member * CPM + ch;
            int l = hh >> 7;
            float fm = (l == 0) ? fm0 : (l == 1) ? fm1 : 1.f;
            float im = (l == 0) ? 1.f : (l == 1) ? im1 : im2;

            float fg = sig_fast(row[6 + ch]);
            float ig = sig_fast(row[6 + CPM + ch]);
            float og = sig_fast(row[6 + 2 * CPM + ch]);
            float ci = tanh_fast(row[6 + 3 * CPM + ch]);

            float ov = fm * im;
            float cn = ov * (fg * c_r0 + ig * ci) + (fm - ov) * c_r0 + (im - ov) * ci;
            float hn = og * tanh_fast(cn);
            c_r0 = cn;

            unsigned hpk = (unsigned)f2bf(hn);
            unsigned partner = (unsigned)__shfl((int)hpk, (lane + 16) & 63);
            if (!(ch & 1)) {
                unsigned word = hpk | (partner << 16);
                __hip_atomic_store(
                    (unsigned*)(hbf + ((size_t)t * B_ + b0 + b) * H_ + hh),
                    word, __ATOMIC_RELAXED, __HIP_MEMORY_SCOPE_AGENT);
            }
            if (member == 0 && ch == 0)
                dis[t * B_ + b0 + b] = 1.f - (fm0 + fm1 + 1.f) * (1.f / 3.f);
        }
        // no trailing sync: consumers spin on the data itself
    }
}

// ---------------- fused post: TT=2 conv + NT stores + XCD-t-locality swizzle --------
__global__ __launch_bounds__(512, 1)
void k_post(const unsigned short* __restrict__ hbf, const float* __restrict__ dis,
            const unsigned short* __restrict__ Wg,
            const unsigned short* __restrict__ WsT, const unsigned short* __restrict__ WrsT,
            const float* __restrict__ bs, const float* __restrict__ brs,
            const float* __restrict__ bc, float* __restrict__ out_part)
{
    extern __shared__ char plds[];
    float* ldl = (float*)plds;                                   // [2][64][10] 5120
    unsigned short* AlB = (unsigned short*)(plds + 5120);        // [2][2][64][40] 40960
    unsigned short* BlB = (unsigned short*)(plds + 46080);       // [2][384][40] 61440
    unsigned short* hbarL = (unsigned short*)(plds + 5120);      // [64][400] (post-conv)
    unsigned short* uL = (unsigned short*)(plds + 56320);        // [64][72]

    // XCD-aware swizzle: consecutive HW blocks round-robin XCDs; give each XCD a
    // contiguous t-range so the K=10 hbf window stays L2-resident per XCD.
    const int bid = blockIdx.x + 4 * blockIdx.y;     // < 512
    const int xcd = bid & 7, slot = bid >> 3;        // slot < 64
    const int tpair = xcd * 16 + (slot >> 2);
    const int btile = slot & 3;
    const int b0 = btile * 64;
    const int t0 = tpair * 2;
    const int tid = threadIdx.x;
    const int wave = tid >> 6, lane = tid & 63;
    const int mh = wave >> 2, nq = wave & 3;

    if (tid < 128) {
        int ti = tid >> 6, bi = tid & 63;
        int t = t0 + ti, b = b0 + bi;
        float s = 0.f, sk[K_];
        #pragma unroll
        for (int k = 0; k < K_; ++k) {
            int tau = t - (K_ - 1) + k;
            float d = (tau >= 0) ? dis[tau * B_ + b] : 0.f;
            s += d; sk[k] = s;
        }
        float m = sk[0];
        #pragma unroll
        for (int k = 1; k < K_; ++k) m = fmaxf(m, sk[k]);
        float sum = 0.f;
        #pragma unroll
        for (int k = 0; k < K_; ++k) { sk[k] = __expf(sk[k] - m); sum += sk[k]; }
        float inv = 1.f / sum;
        #pragma unroll
        for (int k = 0; k < K_; ++k) ldl[ti * 640 + bi * 10 + k] = sk[k] * inv;
    }

    const int a_ti = tid >> 8, a_rem = tid & 255;
    const int a_bb = a_rem >> 2, a_half = a_rem & 3;

    auto loadA = [&](int ch, int4& av, bool& valid) {
        int k = ch / 12, hb = (ch % 12) * 32;
        int tau = t0 + a_ti - (K_ - 1) + k;
        valid = (tau >= 0);
        if (valid)
            av = *(const int4*)(hbf + ((size_t)tau * B_ + b0 + a_bb) * H_ + hb + a_half * 8);
    };
    auto loadB = [&](int ch, int4 bv[3]) {
        #pragma unroll
        for (int q = 0; q < 3; ++q) {
            int idx = q * 512 + tid;
            int row = idx >> 2, half = idx & 3;
            bv[q] = *(const int4*)(Wg + (size_t)row * 3840 + ch * 32 + half * 8);
        }
    };
    auto writeA = [&](int buf, int ch, int4 av, bool valid) {
        int k = ch / 12;
        int4 pk = make_int4(0, 0, 0, 0);
        if (valid) {
            float l = ldl[a_ti * 640 + a_bb * 10 + k];
            unsigned vv[4] = {(unsigned)av.x, (unsigned)av.y, (unsigned)av.z, (unsigned)av.w};
            unsigned o[4];
            #pragma unroll
            for (int q = 0; q < 4; ++q) {
                float flo = __uint_as_float(vv[q] << 16) * l;
                float fhi = __uint_as_float(vv[q] & 0xffff0000u) * l;
                o[q] = (unsigned)f2bf(flo) | ((unsigned)f2bf(fhi) << 16);
            }
            pk = make_int4((int)o[0], (int)o[1], (int)o[2], (int)o[3]);
        }
        *(int4*)&AlB[buf * 5120 + a_ti * 2560 + a_bb * 40 + a_half * 8] = pk;
    };
    auto writeB = [&](int buf, const int4 bv[3]) {
        #pragma unroll
        for (int q = 0; q < 3; ++q) {
            int idx = q * 512 + tid;
            int row = idx >> 2, half = idx & 3;
            *(int4*)&BlB[buf * 15360 + row * 40 + half * 8] = bv[q];
        }
    };

    int4 av; bool avalid; int4 bv[3];
    loadA(0, av, avalid); loadB(0, bv);
    __syncthreads();                    // ldl ready
    writeA(0, 0, av, avalid); writeB(0, bv);

    f32x4 acc[2][2][6] = {};
    for (int ch = 0; ch < 120; ++ch) {
        int cur = ch & 1;
        bool more = (ch + 1 < 120);
        if (more) { loadA(ch + 1, av, avalid); loadB(ch + 1, bv); }
        __syncthreads();
        if (more) { writeA(cur ^ 1, ch + 1, av, avalid); writeB(cur ^ 1, bv); }

        bf16x8 af[2][2];
        #pragma unroll
        for (int ti = 0; ti < 2; ++ti)
            #pragma unroll
            for (int mi = 0; mi < 2; ++mi)
                af[ti][mi] = *(const bf16x8*)&AlB[cur * 5120 + ti * 2560
                    + (mh * 32 + mi * 16 + (lane & 15)) * 40 + (lane >> 4) * 8];
        #pragma unroll
        for (int ni = 0; ni < 6; ++ni) {
            bf16x8 bfv = *(const bf16x8*)&BlB[cur * 15360
                + (nq * 96 + ni * 16 + (lane & 15)) * 40 + (lane >> 4) * 8];
            #pragma unroll
            for (int ti = 0; ti < 2; ++ti)
                #pragma unroll
                for (int mi = 0; mi < 2; ++mi)
                    acc[ti][mi][ni] = __builtin_amdgcn_mfma_f32_16x16x32_bf16(
                        af[ti][mi], bfv, acc[ti][mi][ni], 0, 0, 0);
        }
    }
    __syncthreads();

    #pragma unroll
    for (int ti = 0; ti < 2; ++ti) {
        const int t = t0 + ti;
        for (int idx = tid; idx < 3072; idx += 512) {
            int bb = idx / 48, h8 = idx % 48;
            float s[8] = {};
            #pragma unroll
            for (int k = 0; k < K_; ++k) {
                int tau = t - (K_ - 1) + k;
                if (tau >= 0) {
                    int4 v = *(const int4*)(hbf + ((size_t)tau * B_ + b0 + bb) * H_ + h8 * 8);
                    float l = ldl[ti * 640 + bb * 10 + k];
                    unsigned vv[4] = {(unsigned)v.x, (unsigned)v.y, (unsigned)v.z, (unsigned)v.w};
                    #pragma unroll
                    for (int q = 0; q < 4; ++q) {
                        s[2 * q]     = fmaf(__uint_as_float(vv[q] << 16), l, s[2 * q]);
                        s[2 * q + 1] = fmaf(__uint_as_float(vv[q] & 0xffff0000u), l, s[2 * q + 1]);
                    }
                }
            }
            unsigned o[4];
            #pragma unroll
            for (int q = 0; q < 4; ++q)
                o[q] = (unsigned)f2bf(s[2 * q] * 0.1f) | ((unsigned)f2bf(s[2 * q + 1] * 0.1f) << 16);
            *(int4*)&hbarL[bb * 400 + h8 * 8] = make_int4((int)o[0], (int)o[1], (int)o[2], (int)o[3]);
        }
        __syncthreads();

        if (wave < 4) {
            f32x4 uacc[4] = {};
            for (int kc = 0; kc < 12; ++kc) {
                bf16x8 a = *(const bf16x8*)&hbarL[(wave * 16 + (lane & 15)) * 400
                                                  + kc * 32 + (lane >> 4) * 8];
                #pragma unroll
                for (int ni = 0; ni < 4; ++ni) {
                    bf16x8 wb = *(const bf16x8*)(WsT + (size_t)(ni * 16 + (lane & 15)) * H_
                                                 + kc * 32 + (lane >> 4) * 8);
                    uacc[ni] = __builtin_amdgcn_mfma_f32_16x16x32_bf16(a, wb, uacc[ni], 0, 0, 0);
                }
            }
            #pragma unroll
            for (int ni = 0; ni < 4; ++ni) {
                float bsv = bs[ni * 16 + (lane & 15)];
                #pragma unroll
                for (int r = 0; r < 4; ++r)
                    uL[(wave * 16 + (lane >> 4) * 4 + r) * 72 + ni * 16 + (lane & 15)] =
                        f2bf(fmaxf(uacc[ni][r] + bsv, 0.f));
            }
        }
        __syncthreads();

        #pragma unroll
        for (int half = 0; half < 2; ++half) {
            f32x4 tacc[2][3] = {};
            #pragma unroll
            for (int kc = 0; kc < 2; ++kc) {
                bf16x8 ua[2];
                #pragma unroll
                for (int mi = 0; mi < 2; ++mi)
                    ua[mi] = *(const bf16x8*)&uL[(mh * 32 + mi * 16 + (lane & 15)) * 72
                                                 + kc * 32 + (lane >> 4) * 8];
                #pragma unroll
                for (int n3 = 0; n3 < 3; ++n3) {
                    int ni = half * 3 + n3;
                    bf16x8 wb = *(const bf16x8*)(WrsT
                        + (size_t)(nq * 96 + ni * 16 + (lane & 15)) * HS_
                        + kc * 32 + (lane >> 4) * 8);
                    #pragma unroll
                    for (int mi = 0; mi < 2; ++mi)
                        tacc[mi][n3] = __builtin_amdgcn_mfma_f32_16x16x32_bf16(
                            ua[mi], wb, tacc[mi][n3], 0, 0, 0);
                }
            }
            #pragma unroll
            for (int mi = 0; mi < 2; ++mi) {
                #pragma unroll
                for (int n3 = 0; n3 < 3; ++n3) {
                    int ni = half * 3 + n3;
                    int o = nq * 96 + ni * 16 + (lane & 15);
                    float brsv = brs[o], bcv = bc[o];
                    int brow0 = b0 + mh * 32 + mi * 16 + ((lane >> 4) << 2);
                    #pragma unroll
                    for (int r = 0; r < 4; ++r) {
                        float th = sig_fast(tacc[mi][n3][r] + brsv);
                        float cv = acc[ti][mi][ni][r] + bcv;
                        float hv = bf2f(hbf[((size_t)t * B_ + brow0 + r) * H_ + o]);
                        __builtin_nontemporal_store(hv + th * cv,
                            out_part + ((size_t)(brow0 + r) * T_ + t) * H_ + o);
                    }
                }
            }
        }
        __syncthreads();
    }
}

// ---------------- last_output gather ----------------
__global__ void k_last(const int* __restrict__ len_i, const float* __restrict__ out_part,
                       float* __restrict__ last)
{
    int b = blockIdx.x, tid = threadIdx.x;
    bool is64 = (len_i[1] == 0);
    long long v = is64 ? ((const long long*)len_i)[b] : (long long)len_i[b];
    int idx = (int)v;
    idx = max(1, min(T_, idx)) - 1;
    last[(size_t)b * H_ + tid] = out_part[((size_t)b * T_ + idx) * H_ + tid];
}

extern "C" void kernel_launch(void* const* d_in, const int* in_sizes, int n_in,
                              void* d_out, int out_size, void* d_ws, size_t ws_size,
                              hipStream_t stream) {
    const float* x   = (const float*)d_in[0];
    const int*   len = (const int*)d_in[1];
    const float* Wk  = (const float*)d_in[2];
    const float* bk  = (const float*)d_in[3];
    const float* Wr  = (const float*)d_in[4];
    const float* br  = (const float*)d_in[5];
    const float* Ws  = (const float*)d_in[6];
    const float* bs  = (const float*)d_in[7];
    const float* Wrs = (const float*)d_in[8];
    const float* brs = (const float*)d_in[9];
    const float* Wc  = (const float*)d_in[10];
    const float* bc  = (const float*)d_in[11];

    float* out      = (float*)d_out;
    float* last     = out;
    float* out_part = out + (size_t)B_ * H_;

    // workspace layout (bytes), total ~90 MB
    char* p = (char*)d_ws;
    float*          dis    = (float*)p;          p += (size_t)T_ * B_ * 4;
    unsigned short* xA     = (unsigned short*)p; p += (size_t)T_ * B_ * D_ * 2;
    unsigned short* WfragG = (unsigned short*)p; p += (size_t)NMEM * NKC * NFR * 64 * 8 * 2;
    float*          biasP  = (float*)p;          p += (size_t)NMEM * PCOLS * 4;
    unsigned short* hbf    = (unsigned short*)p; p += (size_t)T_ * B_ * H_ * 2;
    unsigned short* Wg     = (unsigned short*)p; p += (size_t)H_ * K_ * H_ * 2;
    unsigned short* WsT    = (unsigned short*)p; p += (size_t)HS_ * H_ * 2;
    unsigned short* WrsT   = (unsigned short*)p; p += (size_t)H_ * HS_ * 2;

    k_xa  <<<dim3(T_, 4), 256, 0, stream>>>(x, xA);
    k_prep<<<8567, 256, 0, stream>>>(Wk, bk, Wr, br, Ws, Wrs, Wc,
                                     hbf, WfragG, Wg, WsT, WrsT, biasP);

    hipFuncSetAttribute((const void*)k_serial,
                        hipFuncAttributeMaxDynamicSharedMemorySize, LDS_BYTES);
    hipFuncSetAttribute((const void*)k_post,
                        hipFuncAttributeMaxDynamicSharedMemorySize, POST_LDS);

    k_serial<<<NGRP * NMEM, 512, LDS_BYTES, stream>>>(xA, WfragG, biasP, hbf, dis);
    k_post <<<dim3(4, 128), 512, POST_LDS, stream>>>(hbf, dis, Wg, WsT, WrsT, bs, brs, bc, out_part);
    k_last <<<B_, H_, 0, stream>>>(len, out_part, last);
}

// Round 18
// 1244.444 us; speedup vs baseline: 1.3522x; 1.0315x over previous
//
#include <hip/hip_runtime.h>
#include <hip/hip_bf16.h>
#include <cstddef>

// Problem constants
#define B_  256
#define T_  256
#define D_  256
#define H_  384
#define G_  1542
#define L_  3
#define CH_ 128
#define K_  10
#define HS_ 64

// Serial-phase geometry: 16 groups (16 b each) x 16 members (24 ch, 102 cols -> 7 frags)
#define NGRP 16
#define NMEM 16
#define GW   16
#define CPM  24
#define NFR  7
#define PCOLS 112
#define XOLP 114
#define NKC  20
// k_serial LDS layout (bytes): stage 12 slots (12288) | xol 16*114*4 (7296)
#define STG_BYTES 12288
#define XOL_OFF   STG_BYTES
#define LDS_BYTES (STG_BYTES + XOLP * GW * 4)   // 19584

// k_post LDS (dynamic), t-tile = 2: ldl 5120 | A dbuf 40960 | B dbuf 61440 -> 107520
#define POST_LDS 107520

#define SENT 0xFFFFFFFFFFFFFFFFull

using bf16x8 = __attribute__((ext_vector_type(8))) short;
using f32x4  = __attribute__((ext_vector_type(4))) float;
typedef unsigned long long ull_t;

__device__ __forceinline__ float bf2f(unsigned short s) {
    return __uint_as_float(((unsigned)s) << 16);
}
__device__ __forceinline__ unsigned short f2bf(float f) {
    unsigned u = __float_as_uint(f);
    return (unsigned short)((u + 0x7fffu + ((u >> 16) & 1u)) >> 16);
}
__device__ __forceinline__ float sig_fast(float x) { return 1.f / (1.f + __expf(-x)); }
__device__ __forceinline__ float tanh_fast(float x) {
    float ax = fabsf(x);
    float t = __expf(-2.f * ax);
    float r = (1.f - t) / (1.f + t);
    return copysignf(r, x);
}
__device__ __forceinline__ ull_t ldA(const ull_t* p) {
    return __hip_atomic_load(p, __ATOMIC_RELAXED, __HIP_MEMORY_SCOPE_AGENT);
}
// ready iff NO 16-bit field of v equals 0xFFFF (bf16 -NaN sentinel; h in (-1,1) can't encode it)
__device__ __forceinline__ bool rdy(ull_t v) {
    ull_t x = ~v;
    return (((x - 0x0001000100010001ull) & ~x & 0x8000800080008000ull) == 0ull);
}

// packed col -> gate col (or -1 for pad)
__device__ __forceinline__ int gcol_of(int member, int p) {
    if (p < 6) return p;
    if (p < 102) { int q = p - 6; return 6 + (q / CPM) * H_ + member * CPM + (q % CPM); }
    return -1;
}

// ---------------- xA: A-frag-ordered x (bf16), coalesced via LDS ----------------
__global__ __launch_bounds__(256)
void k_xa(const float* __restrict__ x, unsigned short* __restrict__ xA) {
    __shared__ float xl[64][261];
    const int t = blockIdx.x, bq = blockIdx.y;
    const int b0 = bq * 64, tid = threadIdx.x;
    for (int idx = tid; idx < 4096; idx += 256) {
        int row = idx >> 6, c4 = idx & 63;
        float4 v = *(const float4*)(x + ((size_t)(b0 + row) * T_ + t) * D_ + c4 * 4);
        xl[row][c4 * 4 + 0] = v.x; xl[row][c4 * 4 + 1] = v.y;
        xl[row][c4 * 4 + 2] = v.z; xl[row][c4 * 4 + 3] = v.w;
    }
    __syncthreads();
    for (int idx = tid; idx < 2048; idx += 256) {
        int lane = idx & 63, gl = (idx >> 6) & 3, kc = idx >> 8;
        int brow = gl * 16 + (lane & 15);
        int d = kc * 32 + (lane >> 4) * 8;
        unsigned o[4];
        #pragma unroll
        for (int q = 0; q < 4; ++q)
            o[q] = (unsigned)f2bf(xl[brow][d + 2 * q])
                 | ((unsigned)f2bf(xl[brow][d + 2 * q + 1]) << 16);
        int4 pk = make_int4((int)o[0], (int)o[1], (int)o[2], (int)o[3]);
        ((int4*)xA)[(((size_t)t * 8 + kc) * 16 + (bq * 4 + gl)) * 64 + lane] = pk;
    }
}

// ---------------- merged prep: hbf sentinel + wfrag + wg + wst + wrst + bias -------
__global__ __launch_bounds__(256)
void k_prep(const float* __restrict__ Wk, const float* __restrict__ bk,
            const float* __restrict__ Wr, const float* __restrict__ br,
            const float* __restrict__ Ws, const float* __restrict__ Wrs,
            const float* __restrict__ Wc,
            unsigned short* __restrict__ hbf, unsigned short* __restrict__ Wf,
            unsigned short* __restrict__ Wg, unsigned short* __restrict__ WsT,
            unsigned short* __restrict__ WrsT, float* __restrict__ biasP)
{
    const int bid = blockIdx.x, tid = threadIdx.x;
    if (bid < 2048) {
        ull_t* hb = (ull_t*)hbf;
        int base = bid * 256 + tid;
        #pragma unroll
        for (int j = 0; j < 12; ++j)
            __hip_atomic_store(hb + base + j * 524288, SENT,
                               __ATOMIC_RELAXED, __HIP_MEMORY_SCOPE_AGENT);
    } else if (bid < 2608) {
        int idx = (bid - 2048) * 256 + tid;          // < 143360
        int lane = idx & 63;
        int ni   = (idx >> 6) % NFR;
        int kc   = (idx / (64 * NFR)) % NKC;
        int member = idx / (64 * NFR * NKC);
        int p = ni * 16 + (lane & 15);
        int g = gcol_of(member, p);
        unsigned short out[8];
        #pragma unroll
        for (int j = 0; j < 8; ++j) {
            int k = kc * 32 + (lane >> 4) * 8 + j;
            float v = 0.f;
            if (g >= 0) v = (k < 256) ? Wk[(size_t)k * G_ + g] : Wr[(size_t)(k - 256) * G_ + g];
            out[j] = f2bf(v);
        }
        int4 pk;
        pk.x = (unsigned)out[0] | ((unsigned)out[1] << 16);
        pk.y = (unsigned)out[2] | ((unsigned)out[3] << 16);
        pk.z = (unsigned)out[4] | ((unsigned)out[5] << 16);
        pk.w = (unsigned)out[6] | ((unsigned)out[7] << 16);
        ((int4*)Wf)[idx] = pk;
    } else if (bid < 8368) {
        int idx = (bid - 2608) * 256 + tid;          // < 1474560
        int o = idx / (K_ * H_);
        int rem = idx % (K_ * H_);
        int k = rem / H_, h = rem % H_;
        Wg[idx] = f2bf(Wc[((size_t)o * H_ + h) * K_ + k]);
    } else if (bid < 8464) {
        int idx = (bid - 8368) * 256 + tid;          // < 24576
        int jj = idx / H_, k = idx % H_;
        WsT[idx] = f2bf(Ws[(size_t)k * HS_ + jj]);
    } else if (bid < 8560) {
        int idx = (bid - 8464) * 256 + tid;          // < 24576
        int o = idx / HS_, jj = idx % HS_;
        WrsT[idx] = f2bf(Wrs[(size_t)jj * H_ + o]);
    } else {
        int idx = (bid - 8560) * 256 + tid;
        if (idx < NMEM * PCOLS) {
            int member = idx / PCOLS, p = idx % PCOLS;
            int g = gcol_of(member, p);
            biasP[idx] = (g >= 0)
                ? bk[g] + br[g] + Wk[(size_t)256 * G_ + g] + Wr[(size_t)384 * G_ + g] : 0.f;
        }
    }
}

// ---------------- persistent serial recurrence (register weights, 2 barriers/step) --
__global__ __launch_bounds__(512, 1)
void k_serial(const unsigned short* __restrict__ xA, const unsigned short* __restrict__ Wf,
              const float* __restrict__ biasP,
              unsigned short* __restrict__ hbf, float* __restrict__ dis)
{
    extern __shared__ char lds_raw[];
    int4* stage4 = (int4*)lds_raw;                              // 12 kc x 64 lanes x 16B
    const bf16x8* stage = (const bf16x8*)lds_raw;
    float* xol = (float*)(lds_raw + XOL_OFF);                   // 16 x 114 f32 (disjoint)

    const int tid = threadIdx.x;
    const int lane = tid & 63, wave = tid >> 6;
    const int group = blockIdx.x & 15, member = blockIdx.x >> 4;
    const int b0 = group * GW;
    const int ni = wave;
    const bool domm = (wave < NFR);

    // one-time: weight frags into REGISTERS (80 VGPR; static indexing only)
    bf16x8 wreg[NKC];
    if (domm) {
        const bf16x8* wsrc = (const bf16x8*)(Wf + (size_t)member * (NKC * NFR * 64 * 8));
        #pragma unroll
        for (int kc = 0; kc < NKC; ++kc)
            wreg[kc] = wsrc[(kc * NFR + ni) * 64 + lane];
    }
    const float bias_a = domm ? biasP[member * PCOLS + ni * 16 + (lane & 15)] : 0.f;

    const bool hasS = (tid < 384);
    const int skcl = tid >> 6, sln = tid & 63;
    const int stA = skcl * 64 + sln;
    const int stB = (skcl + 6) * 64 + sln;
    const unsigned short* src0 =
        hbf + (size_t)(b0 + (sln & 15)) * H_ + skcl * 32 + (sln >> 4) * 8;

    float c_r0 = 0.f;

    for (int t = 0; t < T_; ++t) {
        bf16x8 xf[8];
        if (domm) {
            #pragma unroll
            for (int kc = 0; kc < 8; ++kc)
                xf[kc] = *((const bf16x8*)(xA
                    + (((size_t)t * 8 + kc) * 16 + group) * 512 + lane * 8));
        }

        // dual accumulator chains (break MFMA dep latency)
        f32x4 accA = f32x4{bias_a, bias_a, bias_a, bias_a};
        f32x4 accB = f32x4{0.f, 0.f, 0.f, 0.f};

        if (t > 0) {
            const size_t toff = (size_t)(t - 1) * B_ * H_;
            const ull_t* pA = (const ull_t*)(src0 + toff);
            const ull_t* pB = (const ull_t*)(src0 + toff + 192);
            ull_t v0 = SENT, v1 = SENT, v2 = SENT, v3 = SENT;
            if (hasS) { v0 = ldA(pA); v1 = ldA(pA + 1); v2 = ldA(pB); v3 = ldA(pB + 1); }

            // x MFMAs (pure-register) overlap the poll flight
            if (domm) {
                #pragma unroll
                for (int kc = 0; kc < 8; ++kc) {
                    if (kc & 1)
                        accB = __builtin_amdgcn_mfma_f32_16x16x32_bf16(xf[kc], wreg[kc], accB, 0, 0, 0);
                    else
                        accA = __builtin_amdgcn_mfma_f32_16x16x32_bf16(xf[kc], wreg[kc], accA, 0, 0, 0);
                }
            }

            if (hasS) {
                while (!(rdy(v0) && rdy(v1) && rdy(v2) && rdy(v3))) {
                    v0 = ldA(pA); v1 = ldA(pA + 1); v2 = ldA(pB); v3 = ldA(pB + 1);
                }
                stage4[stA] = make_int4((int)(v0 & 0xffffffffu), (int)(v0 >> 32),
                                        (int)(v1 & 0xffffffffu), (int)(v1 >> 32));
                stage4[stB] = make_int4((int)(v2 & 0xffffffffu), (int)(v2 >> 32),
                                        (int)(v3 & 0xffffffffu), (int)(v3 >> 32));
            }
            __syncthreads();                                    // S1: stage ready
            if (domm) {
                #pragma unroll
                for (int kcl = 0; kcl < 12; ++kcl) {
                    bf16x8 a0 = stage[kcl * 64 + lane];
                    if (kcl & 1)
                        accB = __builtin_amdgcn_mfma_f32_16x16x32_bf16(a0, wreg[8 + kcl], accB, 0, 0, 0);
                    else
                        accA = __builtin_amdgcn_mfma_f32_16x16x32_bf16(a0, wreg[8 + kcl], accA, 0, 0, 0);
                }
            }
            // NO S2: xol is disjoint from stage; S3(t) orders stage reads(t) vs writes(t+1)
        } else {
            if (domm) {
                #pragma unroll
                for (int kc = 0; kc < 8; ++kc) {
                    if (kc & 1)
                        accB = __builtin_amdgcn_mfma_f32_16x16x32_bf16(xf[kc], wreg[kc], accB, 0, 0, 0);
                    else
                        accA = __builtin_amdgcn_mfma_f32_16x16x32_bf16(xf[kc], wreg[kc], accA, 0, 0, 0);
                }
            }
        }

        if (domm) {
            #pragma unroll
            for (int r = 0; r < 4; ++r)
                xol[((lane >> 4) * 4 + r) * XOLP + ni * 16 + (lane & 15)] = accA[r] + accB[r];
        }
        __syncthreads();                                        // S3: xol ready

        // ---- gates: 384 items; DIRECT publication (paired u32 agent stores) ----
        if (tid < 384) {
            int b = tid & 15, ch = tid >> 4;
            const float* row = xol + b * XOLP;
            float z0 = row[0], z1 = row[1], z2 = row[2];
            float z3 = row[3], z4 = row[4], z5 = row[5];
            float m1 = fmaxf(fmaxf(z0, z1), z2);
            float e0 = __expf(z0 - m1), e1 = __expf(z1 - m1), e2 = __expf(z2 - m1);
            float inv1 = 1.f / (e0 + e1 + e2);
            float fm0 = e0 * inv1, fm1 = (e0 + e1) * inv1;
            float m2 = fmaxf(fmaxf(z3, z4), z5);
            float f3 = __expf(z3 - m2), f4 = __expf(z4 - m2), f5 = __expf(z5 - m2);
            float inv2 = 1.f / (f3 + f4 + f5);
            float im1 = (f4 + f5) * inv2, im2 = f5 * inv2;

            int hh = member * CPM + ch;
            int l = hh >> 7;
            float fm = (l == 0) ? fm0 : (l == 1) ? fm1 : 1.f;
            float im = (l == 0) ? 1.f : (l == 1) ? im1 : im2;

            float fg = sig_fast(row[6 + ch]);
            float ig = sig_fast(row[6 + CPM + ch]);
            float og = sig_fast(row[6 + 2 * CPM + ch]);
            float ci = tanh_fast(row[6 + 3 * CPM + ch]);

            float ov = fm * im;
            float cn = ov * (fg * c_r0 + ig * ci) + (fm - ov) * c_r0 + (im - ov) * ci;
            float hn = og * tanh_fast(cn);
            c_r0 = cn;

            unsigned hpk = (unsigned)f2bf(hn);
            unsigned partner = (unsigned)__shfl((int)hpk, (lane + 16) & 63);
            if (!(ch & 1)) {
                unsigned word = hpk | (partner << 16);
                __hip_atomic_store(
                    (unsigned*)(hbf + ((size_t)t * B_ + b0 + b) * H_ + hh),
                    word, __ATOMIC_RELAXED, __HIP_MEMORY_SCOPE_AGENT);
            }
            if (member == 0 && ch == 0)
                dis[t * B_ + b0 + b] = 1.f - (fm0 + fm1 + 1.f) * (1.f / 3.f);
        }
        // no trailing sync: consumers spin on the data itself
    }
}

// ---------------- fused post: TT=2 conv + NT stores + XCD-t-locality swizzle --------
__global__ __launch_bounds__(512, 1)
void k_post(const unsigned short* __restrict__ hbf, const float* __restrict__ dis,
            const unsigned short* __restrict__ Wg,
            const unsigned short* __restrict__ WsT, const unsigned short* __restrict__ WrsT,
            const float* __restrict__ bs, const float* __restrict__ brs,
            const float* __restrict__ bc, float* __restrict__ out_part)
{
    extern __shared__ char plds[];
    float* ldl = (float*)plds;                                   // [2][64][10] 5120
    unsigned short* AlB = (unsigned short*)(plds + 5120);        // [2][2][64][40] 40960
    unsigned short* BlB = (unsigned short*)(plds + 46080);       // [2][384][40] 61440
    unsigned short* hbarL = (unsigned short*)(plds + 5120);      // [64][400] (post-conv)
    unsigned short* uL = (unsigned short*)(plds + 56320);        // [64][72]

    // XCD-aware swizzle: each XCD owns a contiguous t-range -> K=10 hbf window L2-resident
    const int bid = blockIdx.x + 4 * blockIdx.y;     // < 512
    const int xcd = bid & 7, slot = bid >> 3;        // slot < 64
    const int tpair = xcd * 16 + (slot >> 2);
    const int btile = slot & 3;
    const int b0 = btile * 64;
    const int t0 = tpair * 2;
    const int tid = threadIdx.x;
    const int wave = tid >> 6, lane = tid & 63;
    const int mh = wave >> 2, nq = wave & 3;

    if (tid < 128) {
        int ti = tid >> 6, bi = tid & 63;
        int t = t0 + ti, b = b0 + bi;
        float s = 0.f, sk[K_];
        #pragma unroll
        for (int k = 0; k < K_; ++k) {
            int tau = t - (K_ - 1) + k;
            float d = (tau >= 0) ? dis[tau * B_ + b] : 0.f;
            s += d; sk[k] = s;
        }
        float m = sk[0];
        #pragma unroll
        for (int k = 1; k < K_; ++k) m = fmaxf(m, sk[k]);
        float sum = 0.f;
        #pragma unroll
        for (int k = 0; k < K_; ++k) { sk[k] = __expf(sk[k] - m); sum += sk[k]; }
        float inv = 1.f / sum;
        #pragma unroll
        for (int k = 0; k < K_; ++k) ldl[ti * 640 + bi * 10 + k] = sk[k] * inv;
    }

    const int a_ti = tid >> 8, a_rem = tid & 255;
    const int a_bb = a_rem >> 2, a_half = a_rem & 3;

    auto loadA = [&](int ch, int4& av, bool& valid) {
        int k = ch / 12, hb = (ch % 12) * 32;
        int tau = t0 + a_ti - (K_ - 1) + k;
        valid = (tau >= 0);
        if (valid)
            av = *(const int4*)(hbf + ((size_t)tau * B_ + b0 + a_bb) * H_ + hb + a_half * 8);
    };
    auto loadB = [&](int ch, int4 bv[3]) {
        #pragma unroll
        for (int q = 0; q < 3; ++q) {
            int idx = q * 512 + tid;
            int row = idx >> 2, half = idx & 3;
            bv[q] = *(const int4*)(Wg + (size_t)row * 3840 + ch * 32 + half * 8);
        }
    };
    auto writeA = [&](int buf, int ch, int4 av, bool valid) {
        int k = ch / 12;
        int4 pk = make_int4(0, 0, 0, 0);
        if (valid) {
            float l = ldl[a_ti * 640 + a_bb * 10 + k];
            unsigned vv[4] = {(unsigned)av.x, (unsigned)av.y, (unsigned)av.z, (unsigned)av.w};
            unsigned o[4];
            #pragma unroll
            for (int q = 0; q < 4; ++q) {
                float flo = __uint_as_float(vv[q] << 16) * l;
                float fhi = __uint_as_float(vv[q] & 0xffff0000u) * l;
                o[q] = (unsigned)f2bf(flo) | ((unsigned)f2bf(fhi) << 16);
            }
            pk = make_int4((int)o[0], (int)o[1], (int)o[2], (int)o[3]);
        }
        *(int4*)&AlB[buf * 5120 + a_ti * 2560 + a_bb * 40 + a_half * 8] = pk;
    };
    auto writeB = [&](int buf, const int4 bv[3]) {
        #pragma unroll
        for (int q = 0; q < 3; ++q) {
            int idx = q * 512 + tid;
            int row = idx >> 2, half = idx & 3;
            *(int4*)&BlB[buf * 15360 + row * 40 + half * 8] = bv[q];
        }
    };

    int4 av; bool avalid; int4 bv[3];
    loadA(0, av, avalid); loadB(0, bv);
    __syncthreads();                    // ldl ready
    writeA(0, 0, av, avalid); writeB(0, bv);

    f32x4 acc[2][2][6] = {};
    for (int ch = 0; ch < 120; ++ch) {
        int cur = ch & 1;
        bool more = (ch + 1 < 120);
        if (more) { loadA(ch + 1, av, avalid); loadB(ch + 1, bv); }
        __syncthreads();
        if (more) { writeA(cur ^ 1, ch + 1, av, avalid); writeB(cur ^ 1, bv); }

        bf16x8 af[2][2];
        #pragma unroll
        for (int ti = 0; ti < 2; ++ti)
            #pragma unroll
            for (int mi = 0; mi < 2; ++mi)
                af[ti][mi] = *(const bf16x8*)&AlB[cur * 5120 + ti * 2560
                    + (mh * 32 + mi * 16 + (lane & 15)) * 40 + (lane >> 4) * 8];
        #pragma unroll
        for (int ni = 0; ni < 6; ++ni) {
            bf16x8 bfv = *(const bf16x8*)&BlB[cur * 15360
                + (nq * 96 + ni * 16 + (lane & 15)) * 40 + (lane >> 4) * 8];
            #pragma unroll
            for (int ti = 0; ti < 2; ++ti)
                #pragma unroll
                for (int mi = 0; mi < 2; ++mi)
                    acc[ti][mi][ni] = __builtin_amdgcn_mfma_f32_16x16x32_bf16(
                        af[ti][mi], bfv, acc[ti][mi][ni], 0, 0, 0);
        }
    }
    __syncthreads();

    #pragma unroll
    for (int ti = 0; ti < 2; ++ti) {
        const int t = t0 + ti;
        for (int idx = tid; idx < 3072; idx += 512) {
            int bb = idx / 48, h8 = idx % 48;
            float s[8] = {};
            #pragma unroll
            for (int k = 0; k < K_; ++k) {
                int tau = t - (K_ - 1) + k;
                if (tau >= 0) {
                    int4 v = *(const int4*)(hbf + ((size_t)tau * B_ + b0 + bb) * H_ + h8 * 8);
                    float l = ldl[ti * 640 + bb * 10 + k];
                    unsigned vv[4] = {(unsigned)v.x, (unsigned)v.y, (unsigned)v.z, (unsigned)v.w};
                    #pragma unroll
                    for (int q = 0; q < 4; ++q) {
                        s[2 * q]     = fmaf(__uint_as_float(vv[q] << 16), l, s[2 * q]);
                        s[2 * q + 1] = fmaf(__uint_as_float(vv[q] & 0xffff0000u), l, s[2 * q + 1]);
                    }
                }
            }
            unsigned o[4];
            #pragma unroll
            for (int q = 0; q < 4; ++q)
                o[q] = (unsigned)f2bf(s[2 * q] * 0.1f) | ((unsigned)f2bf(s[2 * q + 1] * 0.1f) << 16);
            *(int4*)&hbarL[bb * 400 + h8 * 8] = make_int4((int)o[0], (int)o[1], (int)o[2], (int)o[3]);
        }
        __syncthreads();

        if (wave < 4) {
            f32x4 uacc[4] = {};
            for (int kc = 0; kc < 12; ++kc) {
                bf16x8 a = *(const bf16x8*)&hbarL[(wave * 16 + (lane & 15)) * 400
                                                  + kc * 32 + (lane >> 4) * 8];
                #pragma unroll
                for (int ni = 0; ni < 4; ++ni) {
                    bf16x8 wb = *(const bf16x8*)(WsT + (size_t)(ni * 16 + (lane & 15)) * H_
                                                 + kc * 32 + (lane >> 4) * 8);
                    uacc[ni] = __builtin_amdgcn_mfma_f32_16x16x32_bf16(a, wb, uacc[ni], 0, 0, 0);
                }
            }
            #pragma unroll
            for (int ni = 0; ni < 4; ++ni) {
                float bsv = bs[ni * 16 + (lane & 15)];
                #pragma unroll
                for (int r = 0; r < 4; ++r)
                    uL[(wave * 16 + (lane >> 4) * 4 + r) * 72 + ni * 16 + (lane & 15)] =
                        f2bf(fmaxf(uacc[ni][r] + bsv, 0.f));
            }
        }
        __syncthreads();

        #pragma unroll
        for (int half = 0; half < 2; ++half) {
            f32x4 tacc[2][3] = {};
            #pragma unroll
            for (int kc = 0; kc < 2; ++kc) {
                bf16x8 ua[2];
                #pragma unroll
                for (int mi = 0; mi < 2; ++mi)
                    ua[mi] = *(const bf16x8*)&uL[(mh * 32 + mi * 16 + (lane & 15)) * 72
                                                 + kc * 32 + (lane >> 4) * 8];
                #pragma unroll
                for (int n3 = 0; n3 < 3; ++n3) {
                    int ni = half * 3 + n3;
                    bf16x8 wb = *(const bf16x8*)(WrsT
                        + (size_t)(nq * 96 + ni * 16 + (lane & 15)) * HS_
                        + kc * 32 + (lane >> 4) * 8);
                    #pragma unroll
                    for (int mi = 0; mi < 2; ++mi)
                        tacc[mi][n3] = __builtin_amdgcn_mfma_f32_16x16x32_bf16(
                            ua[mi], wb, tacc[mi][n3], 0, 0, 0);
                }
            }
            #pragma unroll
            for (int mi = 0; mi < 2; ++mi) {
                #pragma unroll
                for (int n3 = 0; n3 < 3; ++n3) {
                    int ni = half * 3 + n3;
                    int o = nq * 96 + ni * 16 + (lane & 15);
                    float brsv = brs[o], bcv = bc[o];
                    int brow0 = b0 + mh * 32 + mi * 16 + ((lane >> 4) << 2);
                    #pragma unroll
                    for (int r = 0; r < 4; ++r) {
                        float th = sig_fast(tacc[mi][n3][r] + brsv);
                        float cv = acc[ti][mi][ni][r] + bcv;
                        float hv = bf2f(hbf[((size_t)t * B_ + brow0 + r) * H_ + o]);
                        __builtin_nontemporal_store(hv + th * cv,
                            out_part + ((size_t)(brow0 + r) * T_ + t) * H_ + o);
                    }
                }
            }
        }
        __syncthreads();
    }
}

// ---------------- last_output gather ----------------
__global__ void k_last(const int* __restrict__ len_i, const float* __restrict__ out_part,
                       float* __restrict__ last)
{
    int b = blockIdx.x, tid = threadIdx.x;
    bool is64 = (len_i[1] == 0);
    long long v = is64 ? ((const long long*)len_i)[b] : (long long)len_i[b];
    int idx = (int)v;
    idx = max(1, min(T_, idx)) - 1;
    last[(size_t)b * H_ + tid] = out_part[((size_t)b * T_ + idx) * H_ + tid];
}

extern "C" void kernel_launch(void* const* d_in, const int* in_sizes, int n_in,
                              void* d_out, int out_size, void* d_ws, size_t ws_size,
                              hipStream_t stream) {
    const float* x   = (const float*)d_in[0];
    const int*   len = (const int*)d_in[1];
    const float* Wk  = (const float*)d_in[2];
    const float* bk  = (const float*)d_in[3];
    const float* Wr  = (const float*)d_in[4];
    const float* br  = (const float*)d_in[5];
    const float* Ws  = (const float*)d_in[6];
    const float* bs  = (const float*)d_in[7];
    const float* Wrs = (const float*)d_in[8];
    const float* brs = (const float*)d_in[9];
    const float* Wc  = (const float*)d_in[10];
    const float* bc  = (const float*)d_in[11];

    float* out      = (float*)d_out;
    float* last     = out;
    float* out_part = out + (size_t)B_ * H_;

    // workspace layout (bytes), total ~90 MB
    char* p = (char*)d_ws;
    float*          dis    = (float*)p;          p += (size_t)T_ * B_ * 4;
    unsigned short* xA     = (unsigned short*)p; p += (size_t)T_ * B_ * D_ * 2;
    unsigned short* WfragG = (unsigned short*)p; p += (size_t)NMEM * NKC * NFR * 64 * 8 * 2;
    float*          biasP  = (float*)p;          p += (size_t)NMEM * PCOLS * 4;
    unsigned short* hbf    = (unsigned short*)p; p += (size_t)T_ * B_ * H_ * 2;
    unsigned short* Wg     = (unsigned short*)p; p += (size_t)H_ * K_ * H_ * 2;
    unsigned short* WsT    = (unsigned short*)p; p += (size_t)HS_ * H_ * 2;
    unsigned short* WrsT   = (unsigned short*)p; p += (size_t)H_ * HS_ * 2;

    k_xa  <<<dim3(T_, 4), 256, 0, stream>>>(x, xA);
    k_prep<<<8567, 256, 0, stream>>>(Wk, bk, Wr, br, Ws, Wrs, Wc,
                                     hbf, WfragG, Wg, WsT, WrsT, biasP);

    hipFuncSetAttribute((const void*)k_serial,
                        hipFuncAttributeMaxDynamicSharedMemorySize, LDS_BYTES);
    hipFuncSetAttribute((const void*)k_post,
                        hipFuncAttributeMaxDynamicSharedMemorySize, POST_LDS);

    k_serial<<<NGRP * NMEM, 512, LDS_BYTES, stream>>>(xA, WfragG, biasP, hbf, dis);
    k_post <<<dim3(4, 128), 512, POST_LDS, stream>>>(hbf, dis, Wg, WsT, WrsT, bs, brs, bc, out_part);
    k_last <<<B_, H_, 0, stream>>>(len, out_part, last);
}